// Round 3
// baseline (567.826 us; speedup 1.0000x reference)
//
#include <hip/hip_runtime.h>
#include <stdint.h>

// DoomLiquidNet: conv(3->32,k4s2p1) -> conv(32->64,k4s2p1) -> CfC core -> logits
// Inputs are f32 in device memory (detected on device; bf16 fallback kept).
// Heavy compute in bf16 MFMA (16x16x32).
//
// ws layout:
//   a1s   : u32  [2048][32][32][18]  @ 0          150994944 B  (shifted-pair conv1 out)
//   feats : bf16 [2048][16384]       @ 150994944   67108864 B
//   bbT   : bf16 [128][16448]        @ 218103808    4210688 B
//   HT    : bf16 [256][128]          @ 222314496      65536 B
//   w1p   : bf16 [32][64]            @ 222380032       4096 B
//   w2c   : bf16 [64][512]           @ 222384128      65536 B
//   xb    : f32  [2048][128]         @ 222449664    1048576 B
//   rout  : f32  [2048][64]          @ 223498240     524288 B
//   consts: f32  [3048]              @ 224022528      12288 B
//   flag  : int                      @ 224034816          4 B

typedef unsigned short u16;
typedef unsigned int u32;

typedef float f32x4 __attribute__((ext_vector_type(4)));
typedef short s16x8 __attribute__((ext_vector_type(8)));
typedef __bf16 b16x8 __attribute__((ext_vector_type(8)));

template <typename V>
__device__ inline auto mfma_sel(V a, V b, f32x4 c, int)
    -> decltype(__builtin_amdgcn_mfma_f32_16x16x32_bf16(a, b, c, 0, 0, 0)) {
  return __builtin_amdgcn_mfma_f32_16x16x32_bf16(a, b, c, 0, 0, 0);
}
template <typename V>
__device__ inline f32x4 mfma_sel(V a, V b, f32x4 c, long) {
  union UU { V s; b16x8 b; };
  UU ua; ua.s = a;
  UU ub; ub.s = b;
  return __builtin_amdgcn_mfma_f32_16x16x32_bf16(ua.b, ub.b, c, 0, 0, 0);
}
__device__ inline f32x4 mfma16x16x32(s16x8 a, s16x8 b, f32x4 c) {
  return mfma_sel(a, b, c, 0);
}

__device__ inline float bf2f(u16 v) {
  union { u32 i; float f; } x; x.i = ((u32)v) << 16; return x.f;
}
__device__ inline u16 f2bf(float f) {  // round-to-nearest-even
  union { float f; u32 i; } x; x.f = f;
  u32 i = x.i;
  i += 0x7fffu + ((i >> 16) & 1u);
  return (u16)(i >> 16);
}
__device__ inline void bf2x2(u32 u, float& lo, float& hi) {
  union { u32 i; float f; } a, b;
  a.i = u << 16; b.i = u & 0xffff0000u;
  lo = a.f; hi = b.f;
}
__device__ inline float ldf(int isbf, const void* p, size_t i) {
  return isbf ? bf2f(((const u16*)p)[i]) : ((const float*)p)[i];
}
__device__ inline u16 ldb(int isbf, const void* p, size_t i) {
  return isbf ? ((const u16*)p)[i] : f2bf(((const float*)p)[i]);
}
__device__ inline float fast_tanh(float x) {
  float ax = fabsf(x);
  float e = __expf(2.0f * ax);
  float t = 1.0f - 2.0f / (e + 1.0f);
  return copysignf(t, x);
}

// ---------- fused prep: detect + consts + w1p + w2c + bbT + HT + zero xb ----
// grid 1694 blocks x 256:
//  [0,12)    consts    [12,20) w1p    [20,148) w2c
//  [148,662) bbT tiles [662,670) HT   [670,1694) zero xb
__global__ __launch_bounds__(256)
void k_prep_all(const u32* __restrict__ bwords,
                const void* b1, const void* b2, const void* bbb,
                const void* f1b, const void* f2b, const void* tab,
                const void* tbb, const void* oww, const void* obb,
                const void* hx, const void* w1, const void* w2,
                const void* bw, const void* f1w, const void* f2w,
                const void* taw, const void* tbw,
                float* __restrict__ consts, u16* __restrict__ w1p,
                u16* __restrict__ w2c, u16* __restrict__ bbT,
                u16* __restrict__ HT, float* __restrict__ xb,
                int* __restrict__ flag) {
  __shared__ u16 t[64][65];
  const int tid = threadIdx.x;
  const int b = blockIdx.x;
  // inline dtype detect (every wave; identical result)
  const u32 wd = bwords[tid & 63];
  const u32 ex = (wd >> 7) & 0xFFu;
  unsigned long long m = __ballot(ex >= 100u && ex <= 126u);
  const int isbf = (__popcll(m) >= 32) ? 1 : 0;
  if (b == 0 && tid == 0) *flag = isbf;

  if (b < 12) {
    const int e = b * 256 + tid;
    if (e >= 3048) return;
    float v;
    if (e < 32)        v = ldf(isbf, b1, e);
    else if (e < 96)   v = ldf(isbf, b2, e - 32);
    else if (e < 224)  v = ldf(isbf, bbb, e - 96);
    else if (e < 288)  v = ldf(isbf, f1b, e - 224);
    else if (e < 352)  v = ldf(isbf, f2b, e - 288);
    else if (e < 416)  v = ldf(isbf, tab, e - 352);
    else if (e < 480)  v = ldf(isbf, tbb, e - 416);
    else if (e < 992)  v = ldf(isbf, oww, e - 480);
    else if (e < 1000) v = ldf(isbf, obb, e - 992);
    else               v = ldf(isbf, hx, e - 1000);
    consts[e] = v;
  } else if (b < 20) {
    const int e = (b - 12) * 256 + tid;
    const int k = e & 63, co = e >> 6;
    w1p[e] = (k < 48) ? ldb(isbf, w1, co * 48 + k) : (u16)0;
  } else if (b < 148) {
    const int e = (b - 20) * 256 + tid;
    w2c[e] = ldb(isbf, w2, e);
  } else if (b < 662) {
    const int idx = b - 148;
    const int k0 = (idx >> 1) * 64, j0 = (idx & 1) * 64;
    #pragma unroll
    for (int i = 0; i < 16; ++i) {
      int e = tid + 256 * i;
      int kl = e >> 6, jl = e & 63;
      t[kl][jl] = ldb(isbf, bw, (size_t)(k0 + kl) * 128 + j0 + jl);
    }
    __syncthreads();
    #pragma unroll
    for (int i = 0; i < 16; ++i) {
      int e = tid + 256 * i;
      int jl = e >> 6, kl = e & 63;
      bbT[(size_t)(j0 + jl) * 16448 + k0 + kl] = t[kl][jl];
    }
  } else if (b < 670) {
    const int idx = b - 662;
    const int h = idx >> 1, i0 = (idx & 1) * 64;
    const void* W = (h == 0) ? f1w : (h == 1) ? f2w : (h == 2) ? taw : tbw;
    #pragma unroll
    for (int i = 0; i < 16; ++i) {
      int e = tid + 256 * i;
      int il = e >> 6, cl = e & 63;
      t[il][cl] = ldb(isbf, W, (i0 + il) * 64 + cl);
    }
    __syncthreads();
    #pragma unroll
    for (int i = 0; i < 16; ++i) {
      int e = tid + 256 * i;
      int cl = e >> 6, il = e & 63;
      HT[(h * 64 + cl) * 128 + i0 + il] = t[il][cl];
    }
  } else {
    const int e = (b - 670) * 256 + tid;  // < 262144
    xb[e] = 0.f;
  }
}

// ---------- conv1: implicit GEMM; writes a1s in shifted-pair layout ----------
__global__ __launch_bounds__(256)
void k_conv1(const int* __restrict__ flagp, const void* __restrict__ x,
             const u16* __restrict__ w1p, const float* __restrict__ consts,
             u32* __restrict__ a1s) {
  __shared__ u32 lx[4 * 18 * 34];      // 9792 B
  __shared__ u32 bounce[256 * 17];     // 17408 B (pad 16->17 vs bank conflicts)
  const int isbf = *flagp;
  const int n = blockIdx.x >> 2;
  const int oh0 = (blockIdx.x & 3) * 8;
  const int tid = threadIdx.x;
  // staging: 4 ci-planes (3 real + 1 zero K-pad) x 18 rows x 16 lanes
  for (int task = tid; task < 1152; task += 256) {
    const int row = task >> 4, tt = task & 15;
    const int ci = row / 18, ihp = row - ci * 18;
    const int ih = 2 * oh0 - 1 + ihp;
    u32* dst = &lx[row * 34];
    if (ci == 3 || ih < 0 || ih > 63) {
      dst[2 * tt] = 0u; dst[2 * tt + 1] = 0u;
      if (tt == 15) { dst[32] = 0u; dst[33] = 0u; }
    } else if (!isbf) {
      const float* src = (const float*)x + (((size_t)n * 3 + ci) * 64 + ih) * 64;
      const f32x4 v = *(const f32x4*)(src + 4 * tt);
      const float pv = tt ? src[4 * tt - 1] : 0.f;
      dst[2 * tt]     = (u32)f2bf(pv)   | (((u32)f2bf(v[0])) << 16);
      dst[2 * tt + 1] = (u32)f2bf(v[1]) | (((u32)f2bf(v[2])) << 16);
      if (tt == 15) { dst[32] = (u32)f2bf(v[3]); dst[33] = 0u; }
    } else {
      const u16* src = (const u16*)x + (((size_t)n * 3 + ci) * 64 + ih) * 64;
      const u16 v0 = src[4 * tt], v1 = src[4 * tt + 1];
      const u16 v2 = src[4 * tt + 2], v3 = src[4 * tt + 3];
      const u16 pv = tt ? src[4 * tt - 1] : (u16)0;
      dst[2 * tt]     = (u32)pv | (((u32)v0) << 16);
      dst[2 * tt + 1] = (u32)v1 | (((u32)v2) << 16);
      if (tt == 15) { dst[32] = (u32)v3; dst[33] = 0u; }
    }
  }
  __syncthreads();
  const int w = tid >> 6, lane = tid & 63, quad = lane >> 4, l15 = lane & 15;
  f32x4 acc[2][4];
  #pragma unroll
  for (int mt = 0; mt < 2; ++mt)
    #pragma unroll
    for (int i = 0; i < 4; ++i) acc[mt][i] = f32x4{0.f, 0.f, 0.f, 0.f};
  #pragma unroll
  for (int kst = 0; kst < 2; ++kst) {
    const int kbase = kst * 32 + quad * 8;
    s16x8 afrag[2];
    #pragma unroll
    for (int mt = 0; mt < 2; ++mt)
      afrag[mt] = *(const s16x8*)(w1p + (mt * 16 + l15) * 64 + kbase);
    const int ci = kbase >> 4;
    const int khb = (quad & 1) * 2;
    #pragma unroll
    for (int i = 0; i < 4; ++i) {
      const int nt = w * 4 + i;
      const int r1 = 2 * (nt >> 1) + khb;
      const int base = (ci * 18 + r1) * 34 + (nt & 1) * 16 + l15;
      union { u32 u[4]; s16x8 v; } bf;
      bf.u[0] = lx[base];
      bf.u[1] = lx[base + 1];
      bf.u[2] = lx[base + 34];
      bf.u[3] = lx[base + 35];
      #pragma unroll
      for (int mt = 0; mt < 2; ++mt)
        acc[mt][i] = mfma16x16x32(afrag[mt], bf.v, acc[mt][i]);
    }
  }
  // epilogue: bias+relu -> bounce (u16 px), then shift-pack rows -> a1s
  u16* bb = (u16*)bounce;
  #pragma unroll
  for (int mt = 0; mt < 2; ++mt)
    #pragma unroll
    for (int r = 0; r < 4; ++r) {
      const int co = mt * 16 + quad * 4 + r;
      const float bias = consts[co];
      #pragma unroll
      for (int i = 0; i < 4; ++i) {
        const int nt = w * 4 + i;
        const int row = co * 8 + (nt >> 1);
        const int ow = (nt & 1) * 16 + l15;
        float v = acc[mt][i][r] + bias;
        v = v > 0.f ? v : 0.f;
        bb[row * 34 + ow] = f2bf(v);
      }
    }
  __syncthreads();
  {
    const int r = tid;
    const int co = r >> 3, oh = oh0 + (r & 7);
    const u32* wrow = &bounce[r * 17];
    u32 s[18];
    s[0] = wrow[0] << 16;
    #pragma unroll
    for (int q = 1; q < 16; ++q) s[q] = (wrow[q - 1] >> 16) | (wrow[q] << 16);
    s[16] = wrow[15] >> 16;
    s[17] = 0u;
    u32* g = a1s + (((size_t)n * 32 + co) * 32 + oh) * 18;
    #pragma unroll
    for (int q = 0; q < 9; ++q)
      *(uint2*)(g + 2 * q) = make_uint2(s[2 * q], s[2 * q + 1]);
  }
}

// ---------- conv2: half-image x K-quarter tiles; pure-copy staging ----------
__global__ __launch_bounds__(256)
void k_conv2(const u32* __restrict__ a1s, const u16* __restrict__ w2c,
             const float* __restrict__ consts, u16* __restrict__ feats) {
  __shared__ u32 lx[8 * 18 * 18];  // 10368 B: [ci 0..7][ihp 0..17][u32 0..17]
  const int n = blockIdx.x >> 1;
  const int half = blockIdx.x & 1;
  const int tid = threadIdx.x;
  const int w = tid >> 6, lane = tid & 63, quad = lane >> 4, l15 = lane & 15;
  const int ih0 = half * 15;       // first interior source row (17 rows)
  const int ihp0 = half ? 0 : 1;   // its LDS row
  f32x4 acc[4][2];
  #pragma unroll
  for (int mt = 0; mt < 4; ++mt)
    #pragma unroll
    for (int oi = 0; oi < 2; ++oi) acc[mt][oi] = f32x4{0.f, 0.f, 0.f, 0.f};
  for (int qrt = 0; qrt < 4; ++qrt) {
    __syncthreads();
    if (tid < 144) {  // zero border row per plane
      const int ci = tid / 18, q = tid - ci * 18;
      lx[(ci * 18 + (half ? 17 : 0)) * 18 + q] = 0u;
    }
    const u32* sb = a1s + ((size_t)n * 32 + qrt * 8) * 576 + ih0 * 18;
    for (int e = tid; e < 1224; e += 256) {  // 8 planes x 153 uint2
      const int ci = e / 153, idx = e - ci * 153;
      const uint2 v = *(const uint2*)(sb + ci * 576 + idx * 2);
      *(uint2*)&lx[(ci * 18 + ihp0) * 18 + idx * 2] = v;
    }
    __syncthreads();
    #pragma unroll
    for (int kst = 0; kst < 4; ++kst) {
      const int kglob = qrt * 4 + kst;
      s16x8 afrag[4];
      #pragma unroll
      for (int mt = 0; mt < 4; ++mt)
        afrag[mt] = *(const s16x8*)(w2c + (mt * 16 + l15) * 512 + kglob * 32 + quad * 8);
      const int ci = kst * 2 + (quad >> 1);
      const int khb = (quad & 1) * 2;
      s16x8 bfrag[2];
      #pragma unroll
      for (int oi = 0; oi < 2; ++oi) {
        const int r1 = 2 * (w * 2 + oi) + khb;
        const int base = (ci * 18 + r1) * 18 + l15;
        union { u32 u[4]; s16x8 v; } bf;
        bf.u[0] = lx[base];
        bf.u[1] = lx[base + 1];
        bf.u[2] = lx[base + 18];
        bf.u[3] = lx[base + 19];
        bfrag[oi] = bf.v;
      }
      #pragma unroll
      for (int mt = 0; mt < 4; ++mt)
        #pragma unroll
        for (int oi = 0; oi < 2; ++oi)
          acc[mt][oi] = mfma16x16x32(afrag[mt], bfrag[oi], acc[mt][oi]);
    }
  }
  #pragma unroll
  for (int mt = 0; mt < 4; ++mt)
    #pragma unroll
    for (int r = 0; r < 4; ++r) {
      const int co = mt * 16 + quad * 4 + r;
      const float bias = consts[32 + co];
      #pragma unroll
      for (int oi = 0; oi < 2; ++oi) {
        const int oh = half * 8 + w * 2 + oi;
        float v = acc[mt][oi][r] + bias;
        v = v > 0.f ? v : 0.f;
        feats[(size_t)n * 16384 + co * 256 + oh * 16 + l15] = f2bf(v);
      }
    }
}

// ---------- xb = feats @ bb_w[:16384]: split-K with f32 atomics ----------
__global__ __launch_bounds__(256)
void k_xb(const u16* __restrict__ feats, const u16* __restrict__ bbT,
          float* __restrict__ xb) {
  const int m0 = blockIdx.x * 64;
  const int kc0 = blockIdx.y * 1024;
  const int tid = threadIdx.x;
  const int w = tid >> 6, lane = tid & 63, quad = lane >> 4, l15 = lane & 15;
  f32x4 acc[4][2];
  #pragma unroll
  for (int mt = 0; mt < 4; ++mt)
    #pragma unroll
    for (int i = 0; i < 2; ++i) acc[mt][i] = f32x4{0.f, 0.f, 0.f, 0.f};
  for (int kst = 0; kst < 32; ++kst) {
    const int k = kc0 + kst * 32 + quad * 8;
    s16x8 afrag[4], bfrag[2];
    #pragma unroll
    for (int mt = 0; mt < 4; ++mt)
      afrag[mt] = *(const s16x8*)(feats + (size_t)(m0 + mt * 16 + l15) * 16384 + k);
    #pragma unroll
    for (int i = 0; i < 2; ++i)
      bfrag[i] = *(const s16x8*)(bbT + (size_t)((w * 2 + i) * 16 + l15) * 16448 + k);
    #pragma unroll
    for (int mt = 0; mt < 4; ++mt)
      #pragma unroll
      for (int i = 0; i < 2; ++i)
        acc[mt][i] = mfma16x16x32(afrag[mt], bfrag[i], acc[mt][i]);
  }
  #pragma unroll
  for (int mt = 0; mt < 4; ++mt)
    #pragma unroll
    for (int i = 0; i < 2; ++i) {
      const int j = (w * 2 + i) * 16 + l15;
      #pragma unroll
      for (int r = 0; r < 4; ++r) {
        const int m = m0 + mt * 16 + quad * 4 + r;
        atomicAdd(&xb[m * 128 + j], acc[mt][i][r]);
      }
    }
}

// ---------- CfC recurrence: one block per batch row, 64 sequential steps ----
__global__ __launch_bounds__(256)
void k_rec(const int* __restrict__ flagp, const float* __restrict__ xb,
           const u16* __restrict__ bbT, const u16* __restrict__ HT,
           const float* __restrict__ consts, float* __restrict__ rout,
           void* __restrict__ outv) {
  __shared__ float h[64];
  __shared__ float part[128];
  __shared__ float bbv[128];
  __shared__ float heads[256];
  const int isbf = *flagp;
  const int b = blockIdx.x;
  const int tid = threadIdx.x;
  const int j = tid & 127;
  const int half = tid >> 7;
  float w1r[32];
  {
    const u32* src = (const u32*)(bbT + (size_t)j * 16448 + 16384 + half * 32);
    #pragma unroll
    for (int q = 0; q < 16; ++q) bf2x2(src[q], w1r[2 * q], w1r[2 * q + 1]);
  }
  float w2r[128];
  {
    const u32* src = (const u32*)(HT + tid * 128);
    #pragma unroll
    for (int q = 0; q < 64; ++q) bf2x2(src[q], w2r[2 * q], w2r[2 * q + 1]);
  }
  const float hbias = consts[224 + tid];
  const float bbias = consts[96 + j];
  if (tid < 64) h[tid] = consts[1000 + b * 64 + tid];
  __syncthreads();
  for (int t = 0; t < 64; ++t) {
    float p0 = 0.f, p1 = 0.f, p2 = 0.f, p3 = 0.f;
    const int hb0 = half * 32;
    #pragma unroll
    for (int q = 0; q < 8; ++q) {
      p0 += h[hb0 + 4 * q + 0] * w1r[4 * q + 0];
      p1 += h[hb0 + 4 * q + 1] * w1r[4 * q + 1];
      p2 += h[hb0 + 4 * q + 2] * w1r[4 * q + 2];
      p3 += h[hb0 + 4 * q + 3] * w1r[4 * q + 3];
    }
    const float psum = (p0 + p1) + (p2 + p3);
    if (half == 0) part[j] = psum;
    __syncthreads();
    if (half == 1) {
      const float s = psum + part[j] + xb[((size_t)b * 64 + t) * 128 + j] + bbias;
      bbv[j] = 1.7159f * fast_tanh(0.666f * s);
    }
    __syncthreads();
    float c0 = 0.f, c1 = 0.f, c2 = 0.f, c3 = 0.f;
    #pragma unroll
    for (int q = 0; q < 32; ++q) {
      c0 += bbv[4 * q + 0] * w2r[4 * q + 0];
      c1 += bbv[4 * q + 1] * w2r[4 * q + 1];
      c2 += bbv[4 * q + 2] * w2r[4 * q + 2];
      c3 += bbv[4 * q + 3] * w2r[4 * q + 3];
    }
    heads[tid] = (c0 + c1) + (c2 + c3) + hbias;
    __syncthreads();
    if (tid < 64) {
      const float ff1 = fast_tanh(heads[tid]);
      const float ff2 = fast_tanh(heads[64 + tid]);
      const float ti = 1.f / (1.f + __expf(-(heads[128 + tid] + heads[192 + tid])));
      const float hn = ff1 * (1.f - ti) + ti * ff2;
      h[tid] = hn;
      rout[((size_t)b * 64 + t) * 64 + tid] = hn;
    }
    __syncthreads();
  }
  if (tid < 64) {
    if (isbf) ((u16*)outv)[16384 + b * 64 + tid] = f2bf(h[tid]);
    else      ((float*)outv)[16384 + b * 64 + tid] = h[tid];
  }
}

// ---------- logits = rout @ out_w + out_b ----------
__global__ __launch_bounds__(256)
void k_logits(const int* __restrict__ flagp, const float* __restrict__ rout,
              const float* __restrict__ consts, void* __restrict__ outv) {
  __shared__ float W[512];
  __shared__ float Bv[8];
  const int isbf = *flagp;
  const int tid = threadIdx.x;
  for (int e = tid; e < 512; e += 256) W[e] = consts[480 + e];
  if (tid < 8) Bv[tid] = consts[992 + tid];
  __syncthreads();
  const int bt = blockIdx.x * 256 + tid;
  float acc[8];
  #pragma unroll
  for (int c = 0; c < 8; ++c) acc[c] = Bv[c];
  const f32x4* r = (const f32x4*)(rout + (size_t)bt * 64);
  #pragma unroll
  for (int q = 0; q < 16; ++q) {
    f32x4 v = r[q];
    #pragma unroll
    for (int u = 0; u < 4; ++u) {
      const float rv = v[u];
      const int i = 4 * q + u;
      #pragma unroll
      for (int c = 0; c < 8; ++c) acc[c] += rv * W[i * 8 + c];
    }
  }
  if (isbf) {
    u32 pk[4];
    #pragma unroll
    for (int c = 0; c < 4; ++c)
      pk[c] = (u32)f2bf(acc[2 * c]) | ((u32)f2bf(acc[2 * c + 1]) << 16);
    *(uint4*)((u16*)outv + (size_t)bt * 8) = *(const uint4*)pk;
  } else {
    float* o = (float*)outv + (size_t)bt * 8;
    *(f32x4*)o = f32x4{acc[0], acc[1], acc[2], acc[3]};
    *(f32x4*)(o + 4) = f32x4{acc[4], acc[5], acc[6], acc[7]};
  }
}

extern "C" void kernel_launch(void* const* d_in, const int* in_sizes, int n_in,
                              void* d_out, int out_size, void* d_ws, size_t ws_size,
                              hipStream_t stream) {
  const void* x   = d_in[0];
  const void* hx  = d_in[1];
  const void* w1  = d_in[2];
  const void* b1  = d_in[3];
  const void* w2  = d_in[4];
  const void* b2  = d_in[5];
  const void* bbw = d_in[6];
  const void* bbb = d_in[7];
  const void* f1w = d_in[8];
  const void* f1b = d_in[9];
  const void* f2w = d_in[10];
  const void* f2b = d_in[11];
  const void* taw = d_in[12];
  const void* tab = d_in[13];
  const void* tbw = d_in[14];
  const void* tbb = d_in[15];
  const void* oww = d_in[16];
  const void* obb = d_in[17];

  char* ws = (char*)d_ws;
  u32*   a1s   = (u32*)(ws);
  u16*   feats = (u16*)(ws + 150994944);
  u16*   bbT   = (u16*)(ws + 218103808);
  u16*   HT    = (u16*)(ws + 222314496);
  u16*   w1p   = (u16*)(ws + 222380032);
  u16*   w2c   = (u16*)(ws + 222384128);
  float* xb    = (float*)(ws + 222449664);
  float* rout  = (float*)(ws + 223498240);
  float* consts= (float*)(ws + 224022528);
  int*   flag  = (int*)(ws + 224034816);

  k_prep_all<<<1694, 256, 0, stream>>>((const u32*)bbw, b1, b2, bbb, f1b, f2b,
                                       tab, tbb, oww, obb, hx, w1, w2, bbw,
                                       f1w, f2w, taw, tbw,
                                       consts, w1p, w2c, bbT, HT, xb, flag);
  k_conv1<<<8192, 256, 0, stream>>>(flag, x, w1p, consts, a1s);
  k_conv2<<<4096, 256, 0, stream>>>(a1s, w2c, consts, feats);
  k_xb<<<dim3(32, 16), 256, 0, stream>>>(feats, bbT, xb);
  k_rec<<<32, 256, 0, stream>>>(flag, xb, bbT, HT, consts, rout, d_out);
  k_logits<<<8, 256, 0, stream>>>(flag, rout, consts, d_out);
}

// Round 4
// 551.495 us; speedup vs baseline: 1.0296x; 1.0296x over previous
//
#include <hip/hip_runtime.h>
#include <stdint.h>

// DoomLiquidNet: conv(3->32,k4s2p1) -> conv(32->64,k4s2p1) -> CfC core -> logits
// Inputs are f32 in device memory (detected on device; bf16 fallback kept).
// Heavy compute in bf16 MFMA (16x16x32).
//
// conv2 (R4): full-image block (2048 blocks), 16-plane halves, register
// prefetch of the next half's contiguous 36864-B a1s slab so global latency
// overlaps the 128-MFMA block. 3 barriers/block. LDS plane stride 616 u32
// keeps interior rows 16B-aligned for ds_write_b128.
//
// ws layout:
//   a1s   : u32  [2048][32][32][18]  @ 0          150994944 B  (shifted-pair conv1 out)
//   feats : bf16 [2048][16384]       @ 150994944   67108864 B
//   bbT   : bf16 [128][16448]        @ 218103808    4210688 B
//   HT    : bf16 [256][128]          @ 222314496      65536 B
//   w1p   : bf16 [32][64]            @ 222380032       4096 B
//   w2c   : bf16 [64][512]           @ 222384128      65536 B
//   xb    : f32  [2048][128]         @ 222449664    1048576 B
//   rout  : f32  [2048][64]          @ 223498240     524288 B
//   consts: f32  [3048]              @ 224022528      12288 B
//   flag  : int                      @ 224034816          4 B

typedef unsigned short u16;
typedef unsigned int u32;

typedef float f32x4 __attribute__((ext_vector_type(4)));
typedef short s16x8 __attribute__((ext_vector_type(8)));
typedef __bf16 b16x8 __attribute__((ext_vector_type(8)));

template <typename V>
__device__ inline auto mfma_sel(V a, V b, f32x4 c, int)
    -> decltype(__builtin_amdgcn_mfma_f32_16x16x32_bf16(a, b, c, 0, 0, 0)) {
  return __builtin_amdgcn_mfma_f32_16x16x32_bf16(a, b, c, 0, 0, 0);
}
template <typename V>
__device__ inline f32x4 mfma_sel(V a, V b, f32x4 c, long) {
  union UU { V s; b16x8 b; };
  UU ua; ua.s = a;
  UU ub; ub.s = b;
  return __builtin_amdgcn_mfma_f32_16x16x32_bf16(ua.b, ub.b, c, 0, 0, 0);
}
__device__ inline f32x4 mfma16x16x32(s16x8 a, s16x8 b, f32x4 c) {
  return mfma_sel(a, b, c, 0);
}

__device__ inline float bf2f(u16 v) {
  union { u32 i; float f; } x; x.i = ((u32)v) << 16; return x.f;
}
__device__ inline u16 f2bf(float f) {  // round-to-nearest-even
  union { float f; u32 i; } x; x.f = f;
  u32 i = x.i;
  i += 0x7fffu + ((i >> 16) & 1u);
  return (u16)(i >> 16);
}
__device__ inline void bf2x2(u32 u, float& lo, float& hi) {
  union { u32 i; float f; } a, b;
  a.i = u << 16; b.i = u & 0xffff0000u;
  lo = a.f; hi = b.f;
}
__device__ inline float ldf(int isbf, const void* p, size_t i) {
  return isbf ? bf2f(((const u16*)p)[i]) : ((const float*)p)[i];
}
__device__ inline u16 ldb(int isbf, const void* p, size_t i) {
  return isbf ? ((const u16*)p)[i] : f2bf(((const float*)p)[i]);
}
__device__ inline float fast_tanh(float x) {
  float ax = fabsf(x);
  float e = __expf(2.0f * ax);
  float t = 1.0f - 2.0f / (e + 1.0f);
  return copysignf(t, x);
}

// ---------- fused prep: detect + consts + w1p + w2c + bbT + HT + zero xb ----
__global__ __launch_bounds__(256)
void k_prep_all(const u32* __restrict__ bwords,
                const void* b1, const void* b2, const void* bbb,
                const void* f1b, const void* f2b, const void* tab,
                const void* tbb, const void* oww, const void* obb,
                const void* hx, const void* w1, const void* w2,
                const void* bw, const void* f1w, const void* f2w,
                const void* taw, const void* tbw,
                float* __restrict__ consts, u16* __restrict__ w1p,
                u16* __restrict__ w2c, u16* __restrict__ bbT,
                u16* __restrict__ HT, float* __restrict__ xb,
                int* __restrict__ flag) {
  __shared__ u16 t[64][65];
  const int tid = threadIdx.x;
  const int b = blockIdx.x;
  const u32 wd = bwords[tid & 63];
  const u32 ex = (wd >> 7) & 0xFFu;
  unsigned long long m = __ballot(ex >= 100u && ex <= 126u);
  const int isbf = (__popcll(m) >= 32) ? 1 : 0;
  if (b == 0 && tid == 0) *flag = isbf;

  if (b < 12) {
    const int e = b * 256 + tid;
    if (e >= 3048) return;
    float v;
    if (e < 32)        v = ldf(isbf, b1, e);
    else if (e < 96)   v = ldf(isbf, b2, e - 32);
    else if (e < 224)  v = ldf(isbf, bbb, e - 96);
    else if (e < 288)  v = ldf(isbf, f1b, e - 224);
    else if (e < 352)  v = ldf(isbf, f2b, e - 288);
    else if (e < 416)  v = ldf(isbf, tab, e - 352);
    else if (e < 480)  v = ldf(isbf, tbb, e - 416);
    else if (e < 992)  v = ldf(isbf, oww, e - 480);
    else if (e < 1000) v = ldf(isbf, obb, e - 992);
    else               v = ldf(isbf, hx, e - 1000);
    consts[e] = v;
  } else if (b < 20) {
    const int e = (b - 12) * 256 + tid;
    const int k = e & 63, co = e >> 6;
    w1p[e] = (k < 48) ? ldb(isbf, w1, co * 48 + k) : (u16)0;
  } else if (b < 148) {
    const int e = (b - 20) * 256 + tid;
    w2c[e] = ldb(isbf, w2, e);
  } else if (b < 662) {
    const int idx = b - 148;
    const int k0 = (idx >> 1) * 64, j0 = (idx & 1) * 64;
    #pragma unroll
    for (int i = 0; i < 16; ++i) {
      int e = tid + 256 * i;
      int kl = e >> 6, jl = e & 63;
      t[kl][jl] = ldb(isbf, bw, (size_t)(k0 + kl) * 128 + j0 + jl);
    }
    __syncthreads();
    #pragma unroll
    for (int i = 0; i < 16; ++i) {
      int e = tid + 256 * i;
      int jl = e >> 6, kl = e & 63;
      bbT[(size_t)(j0 + jl) * 16448 + k0 + kl] = t[kl][jl];
    }
  } else if (b < 670) {
    const int idx = b - 662;
    const int h = idx >> 1, i0 = (idx & 1) * 64;
    const void* W = (h == 0) ? f1w : (h == 1) ? f2w : (h == 2) ? taw : tbw;
    #pragma unroll
    for (int i = 0; i < 16; ++i) {
      int e = tid + 256 * i;
      int il = e >> 6, cl = e & 63;
      t[il][cl] = ldb(isbf, W, (i0 + il) * 64 + cl);
    }
    __syncthreads();
    #pragma unroll
    for (int i = 0; i < 16; ++i) {
      int e = tid + 256 * i;
      int cl = e >> 6, il = e & 63;
      HT[(h * 64 + cl) * 128 + i0 + il] = t[il][cl];
    }
  } else {
    const int e = (b - 670) * 256 + tid;
    xb[e] = 0.f;
  }
}

// ---------- conv1: implicit GEMM; writes a1s in shifted-pair layout ----------
__global__ __launch_bounds__(256)
void k_conv1(const int* __restrict__ flagp, const void* __restrict__ x,
             const u16* __restrict__ w1p, const float* __restrict__ consts,
             u32* __restrict__ a1s) {
  __shared__ u32 lx[4 * 18 * 34];      // 9792 B
  __shared__ u32 bounce[256 * 17];     // 17408 B
  const int isbf = *flagp;
  const int n = blockIdx.x >> 2;
  const int oh0 = (blockIdx.x & 3) * 8;
  const int tid = threadIdx.x;
  for (int task = tid; task < 1152; task += 256) {
    const int row = task >> 4, tt = task & 15;
    const int ci = row / 18, ihp = row - ci * 18;
    const int ih = 2 * oh0 - 1 + ihp;
    u32* dst = &lx[row * 34];
    if (ci == 3 || ih < 0 || ih > 63) {
      dst[2 * tt] = 0u; dst[2 * tt + 1] = 0u;
      if (tt == 15) { dst[32] = 0u; dst[33] = 0u; }
    } else if (!isbf) {
      const float* src = (const float*)x + (((size_t)n * 3 + ci) * 64 + ih) * 64;
      const f32x4 v = *(const f32x4*)(src + 4 * tt);
      const float pv = tt ? src[4 * tt - 1] : 0.f;
      dst[2 * tt]     = (u32)f2bf(pv)   | (((u32)f2bf(v[0])) << 16);
      dst[2 * tt + 1] = (u32)f2bf(v[1]) | (((u32)f2bf(v[2])) << 16);
      if (tt == 15) { dst[32] = (u32)f2bf(v[3]); dst[33] = 0u; }
    } else {
      const u16* src = (const u16*)x + (((size_t)n * 3 + ci) * 64 + ih) * 64;
      const u16 v0 = src[4 * tt], v1 = src[4 * tt + 1];
      const u16 v2 = src[4 * tt + 2], v3 = src[4 * tt + 3];
      const u16 pv = tt ? src[4 * tt - 1] : (u16)0;
      dst[2 * tt]     = (u32)pv | (((u32)v0) << 16);
      dst[2 * tt + 1] = (u32)v1 | (((u32)v2) << 16);
      if (tt == 15) { dst[32] = (u32)v3; dst[33] = 0u; }
    }
  }
  __syncthreads();
  const int w = tid >> 6, lane = tid & 63, quad = lane >> 4, l15 = lane & 15;
  f32x4 acc[2][4];
  #pragma unroll
  for (int mt = 0; mt < 2; ++mt)
    #pragma unroll
    for (int i = 0; i < 4; ++i) acc[mt][i] = f32x4{0.f, 0.f, 0.f, 0.f};
  #pragma unroll
  for (int kst = 0; kst < 2; ++kst) {
    const int kbase = kst * 32 + quad * 8;
    s16x8 afrag[2];
    #pragma unroll
    for (int mt = 0; mt < 2; ++mt)
      afrag[mt] = *(const s16x8*)(w1p + (mt * 16 + l15) * 64 + kbase);
    const int ci = kbase >> 4;
    const int khb = (quad & 1) * 2;
    #pragma unroll
    for (int i = 0; i < 4; ++i) {
      const int nt = w * 4 + i;
      const int r1 = 2 * (nt >> 1) + khb;
      const int base = (ci * 18 + r1) * 34 + (nt & 1) * 16 + l15;
      union { u32 u[4]; s16x8 v; } bf;
      bf.u[0] = lx[base];
      bf.u[1] = lx[base + 1];
      bf.u[2] = lx[base + 34];
      bf.u[3] = lx[base + 35];
      #pragma unroll
      for (int mt = 0; mt < 2; ++mt)
        acc[mt][i] = mfma16x16x32(afrag[mt], bf.v, acc[mt][i]);
    }
  }
  u16* bb = (u16*)bounce;
  #pragma unroll
  for (int mt = 0; mt < 2; ++mt)
    #pragma unroll
    for (int r = 0; r < 4; ++r) {
      const int co = mt * 16 + quad * 4 + r;
      const float bias = consts[co];
      #pragma unroll
      for (int i = 0; i < 4; ++i) {
        const int nt = w * 4 + i;
        const int row = co * 8 + (nt >> 1);
        const int ow = (nt & 1) * 16 + l15;
        float v = acc[mt][i][r] + bias;
        v = v > 0.f ? v : 0.f;
        bb[row * 34 + ow] = f2bf(v);
      }
    }
  __syncthreads();
  {
    const int r = tid;
    const int co = r >> 3, oh = oh0 + (r & 7);
    const u32* wrow = &bounce[r * 17];
    u32 s[18];
    s[0] = wrow[0] << 16;
    #pragma unroll
    for (int q = 1; q < 16; ++q) s[q] = (wrow[q - 1] >> 16) | (wrow[q] << 16);
    s[16] = wrow[15] >> 16;
    s[17] = 0u;
    u32* g = a1s + (((size_t)n * 32 + co) * 32 + oh) * 18;
    #pragma unroll
    for (int q = 0; q < 9; ++q)
      *(uint2*)(g + 2 * q) = make_uint2(s[2 * q], s[2 * q + 1]);
  }
}

// ---------- conv2: full-image block, reg-prefetch pipelined staging ----------
// LDS plane: [pad 2][borderA 18][interior 32*18=576][borderB 18][pad 2] = 616 u32
__global__ __launch_bounds__(256)
void k_conv2(const u32* __restrict__ a1s, const u16* __restrict__ w2c,
             const float* __restrict__ consts, u16* __restrict__ feats) {
  __shared__ u32 lx[16 * 616];  // 39424 B
  const int n = blockIdx.x;
  const int tid = threadIdx.x;
  const int w = tid >> 6, lane = tid & 63, quad = lane >> 4, l15 = lane & 15;
  f32x4 acc[4][4];
  #pragma unroll
  for (int mt = 0; mt < 4; ++mt)
    #pragma unroll
    for (int oi = 0; oi < 4; ++oi) acc[mt][oi] = f32x4{0.f, 0.f, 0.f, 0.f};

  // prefetch half 0 (contiguous 36864 B = 2304 uint4)
  uint4 pf[9];
  {
    const uint4* src = (const uint4*)(a1s + (size_t)n * 32 * 576);
    #pragma unroll
    for (int i = 0; i < 9; ++i) pf[i] = src[i * 256 + tid];
  }
  // zero borders + pads once (never overwritten by interior stores)
  for (int e = tid; e < 640; e += 256) {
    const int pl = e / 40, o = e - pl * 40;
    lx[pl * 616 + (o < 20 ? o : 576 + o)] = 0u;
  }

  for (int half = 0; half < 2; ++half) {
    // store prefetched regs -> LDS interior (16B-aligned ds_write_b128)
    #pragma unroll
    for (int i = 0; i < 9; ++i) {
      const int s = (i * 256 + tid) * 4;
      const int ci = s / 576;
      *(uint4*)&lx[ci * 616 + 20 + (s - ci * 576)] = pf[i];
    }
    __syncthreads();
    if (half == 0) {  // issue next half's loads; they fly during the MFMAs
      const uint4* src = (const uint4*)(a1s + ((size_t)n * 32 + 16) * 576);
      #pragma unroll
      for (int i = 0; i < 9; ++i) pf[i] = src[i * 256 + tid];
    }
    #pragma unroll
    for (int kst = 0; kst < 8; ++kst) {
      const int kglob = half * 8 + kst;
      s16x8 afrag[4];
      #pragma unroll
      for (int mt = 0; mt < 4; ++mt)
        afrag[mt] = *(const s16x8*)(w2c + (mt * 16 + l15) * 512 + kglob * 32 + quad * 8);
      const int ci = kst * 2 + (quad >> 1);
      const int khb = (quad & 1) * 2;
      s16x8 bfrag[4];
      #pragma unroll
      for (int oi = 0; oi < 4; ++oi) {
        const int r1 = 2 * (w * 4 + oi) + khb;
        const int base = ci * 616 + 20 + (r1 - 1) * 18 + l15;
        union { u32 u[4]; s16x8 v; } bf;
        bf.u[0] = lx[base];
        bf.u[1] = lx[base + 1];
        bf.u[2] = lx[base + 18];
        bf.u[3] = lx[base + 19];
        bfrag[oi] = bf.v;
      }
      #pragma unroll
      for (int mt = 0; mt < 4; ++mt)
        #pragma unroll
        for (int oi = 0; oi < 4; ++oi)
          acc[mt][oi] = mfma16x16x32(afrag[mt], bfrag[oi], acc[mt][oi]);
    }
    if (half == 0) __syncthreads();  // protect LDS before overwrite
  }
  #pragma unroll
  for (int mt = 0; mt < 4; ++mt)
    #pragma unroll
    for (int r = 0; r < 4; ++r) {
      const int co = mt * 16 + quad * 4 + r;
      const float bias = consts[32 + co];
      #pragma unroll
      for (int oi = 0; oi < 4; ++oi) {
        const int oh = w * 4 + oi;
        float v = acc[mt][oi][r] + bias;
        v = v > 0.f ? v : 0.f;
        feats[(size_t)n * 16384 + co * 256 + oh * 16 + l15] = f2bf(v);
      }
    }
}

// ---------- xb = feats @ bb_w[:16384]: split-K with f32 atomics ----------
__global__ __launch_bounds__(256)
void k_xb(const u16* __restrict__ feats, const u16* __restrict__ bbT,
          float* __restrict__ xb) {
  const int m0 = blockIdx.x * 64;
  const int kc0 = blockIdx.y * 1024;
  const int tid = threadIdx.x;
  const int w = tid >> 6, lane = tid & 63, quad = lane >> 4, l15 = lane & 15;
  f32x4 acc[4][2];
  #pragma unroll
  for (int mt = 0; mt < 4; ++mt)
    #pragma unroll
    for (int i = 0; i < 2; ++i) acc[mt][i] = f32x4{0.f, 0.f, 0.f, 0.f};
  for (int kst = 0; kst < 32; ++kst) {
    const int k = kc0 + kst * 32 + quad * 8;
    s16x8 afrag[4], bfrag[2];
    #pragma unroll
    for (int mt = 0; mt < 4; ++mt)
      afrag[mt] = *(const s16x8*)(feats + (size_t)(m0 + mt * 16 + l15) * 16384 + k);
    #pragma unroll
    for (int i = 0; i < 2; ++i)
      bfrag[i] = *(const s16x8*)(bbT + (size_t)((w * 2 + i) * 16 + l15) * 16448 + k);
    #pragma unroll
    for (int mt = 0; mt < 4; ++mt)
      #pragma unroll
      for (int i = 0; i < 2; ++i)
        acc[mt][i] = mfma16x16x32(afrag[mt], bfrag[i], acc[mt][i]);
  }
  #pragma unroll
  for (int mt = 0; mt < 4; ++mt)
    #pragma unroll
    for (int i = 0; i < 2; ++i) {
      const int j = (w * 2 + i) * 16 + l15;
      #pragma unroll
      for (int r = 0; r < 4; ++r) {
        const int m = m0 + mt * 16 + quad * 4 + r;
        atomicAdd(&xb[m * 128 + j], acc[mt][i][r]);
      }
    }
}

// ---------- CfC recurrence: one block per batch row, 64 sequential steps ----
__global__ __launch_bounds__(256)
void k_rec(const int* __restrict__ flagp, const float* __restrict__ xb,
           const u16* __restrict__ bbT, const u16* __restrict__ HT,
           const float* __restrict__ consts, float* __restrict__ rout,
           void* __restrict__ outv) {
  __shared__ float h[64];
  __shared__ float part[128];
  __shared__ float bbv[128];
  __shared__ float heads[256];
  const int isbf = *flagp;
  const int b = blockIdx.x;
  const int tid = threadIdx.x;
  const int j = tid & 127;
  const int half = tid >> 7;
  float w1r[32];
  {
    const u32* src = (const u32*)(bbT + (size_t)j * 16448 + 16384 + half * 32);
    #pragma unroll
    for (int q = 0; q < 16; ++q) bf2x2(src[q], w1r[2 * q], w1r[2 * q + 1]);
  }
  float w2r[128];
  {
    const u32* src = (const u32*)(HT + tid * 128);
    #pragma unroll
    for (int q = 0; q < 64; ++q) bf2x2(src[q], w2r[2 * q], w2r[2 * q + 1]);
  }
  const float hbias = consts[224 + tid];
  const float bbias = consts[96 + j];
  if (tid < 64) h[tid] = consts[1000 + b * 64 + tid];
  __syncthreads();
  for (int t = 0; t < 64; ++t) {
    float p0 = 0.f, p1 = 0.f, p2 = 0.f, p3 = 0.f;
    const int hb0 = half * 32;
    #pragma unroll
    for (int q = 0; q < 8; ++q) {
      p0 += h[hb0 + 4 * q + 0] * w1r[4 * q + 0];
      p1 += h[hb0 + 4 * q + 1] * w1r[4 * q + 1];
      p2 += h[hb0 + 4 * q + 2] * w1r[4 * q + 2];
      p3 += h[hb0 + 4 * q + 3] * w1r[4 * q + 3];
    }
    const float psum = (p0 + p1) + (p2 + p3);
    if (half == 0) part[j] = psum;
    __syncthreads();
    if (half == 1) {
      const float s = psum + part[j] + xb[((size_t)b * 64 + t) * 128 + j] + bbias;
      bbv[j] = 1.7159f * fast_tanh(0.666f * s);
    }
    __syncthreads();
    float c0 = 0.f, c1 = 0.f, c2 = 0.f, c3 = 0.f;
    #pragma unroll
    for (int q = 0; q < 32; ++q) {
      c0 += bbv[4 * q + 0] * w2r[4 * q + 0];
      c1 += bbv[4 * q + 1] * w2r[4 * q + 1];
      c2 += bbv[4 * q + 2] * w2r[4 * q + 2];
      c3 += bbv[4 * q + 3] * w2r[4 * q + 3];
    }
    heads[tid] = (c0 + c1) + (c2 + c3) + hbias;
    __syncthreads();
    if (tid < 64) {
      const float ff1 = fast_tanh(heads[tid]);
      const float ff2 = fast_tanh(heads[64 + tid]);
      const float ti = 1.f / (1.f + __expf(-(heads[128 + tid] + heads[192 + tid])));
      const float hn = ff1 * (1.f - ti) + ti * ff2;
      h[tid] = hn;
      rout[((size_t)b * 64 + t) * 64 + tid] = hn;
    }
    __syncthreads();
  }
  if (tid < 64) {
    if (isbf) ((u16*)outv)[16384 + b * 64 + tid] = f2bf(h[tid]);
    else      ((float*)outv)[16384 + b * 64 + tid] = h[tid];
  }
}

// ---------- logits = rout @ out_w + out_b ----------
__global__ __launch_bounds__(256)
void k_logits(const int* __restrict__ flagp, const float* __restrict__ rout,
              const float* __restrict__ consts, void* __restrict__ outv) {
  __shared__ float W[512];
  __shared__ float Bv[8];
  const int isbf = *flagp;
  const int tid = threadIdx.x;
  for (int e = tid; e < 512; e += 256) W[e] = consts[480 + e];
  if (tid < 8) Bv[tid] = consts[992 + tid];
  __syncthreads();
  const int bt = blockIdx.x * 256 + tid;
  float acc[8];
  #pragma unroll
  for (int c = 0; c < 8; ++c) acc[c] = Bv[c];
  const f32x4* r = (const f32x4*)(rout + (size_t)bt * 64);
  #pragma unroll
  for (int q = 0; q < 16; ++q) {
    f32x4 v = r[q];
    #pragma unroll
    for (int u = 0; u < 4; ++u) {
      const float rv = v[u];
      const int i = 4 * q + u;
      #pragma unroll
      for (int c = 0; c < 8; ++c) acc[c] += rv * W[i * 8 + c];
    }
  }
  if (isbf) {
    u32 pk[4];
    #pragma unroll
    for (int c = 0; c < 4; ++c)
      pk[c] = (u32)f2bf(acc[2 * c]) | ((u32)f2bf(acc[2 * c + 1]) << 16);
    *(uint4*)((u16*)outv + (size_t)bt * 8) = *(const uint4*)pk;
  } else {
    float* o = (float*)outv + (size_t)bt * 8;
    *(f32x4*)o = f32x4{acc[0], acc[1], acc[2], acc[3]};
    *(f32x4*)(o + 4) = f32x4{acc[4], acc[5], acc[6], acc[7]};
  }
}

extern "C" void kernel_launch(void* const* d_in, const int* in_sizes, int n_in,
                              void* d_out, int out_size, void* d_ws, size_t ws_size,
                              hipStream_t stream) {
  const void* x   = d_in[0];
  const void* hx  = d_in[1];
  const void* w1  = d_in[2];
  const void* b1  = d_in[3];
  const void* w2  = d_in[4];
  const void* b2  = d_in[5];
  const void* bbw = d_in[6];
  const void* bbb = d_in[7];
  const void* f1w = d_in[8];
  const void* f1b = d_in[9];
  const void* f2w = d_in[10];
  const void* f2b = d_in[11];
  const void* taw = d_in[12];
  const void* tab = d_in[13];
  const void* tbw = d_in[14];
  const void* tbb = d_in[15];
  const void* oww = d_in[16];
  const void* obb = d_in[17];

  char* ws = (char*)d_ws;
  u32*   a1s   = (u32*)(ws);
  u16*   feats = (u16*)(ws + 150994944);
  u16*   bbT   = (u16*)(ws + 218103808);
  u16*   HT    = (u16*)(ws + 222314496);
  u16*   w1p   = (u16*)(ws + 222380032);
  u16*   w2c   = (u16*)(ws + 222384128);
  float* xb    = (float*)(ws + 222449664);
  float* rout  = (float*)(ws + 223498240);
  float* consts= (float*)(ws + 224022528);
  int*   flag  = (int*)(ws + 224034816);

  k_prep_all<<<1694, 256, 0, stream>>>((const u32*)bbw, b1, b2, bbb, f1b, f2b,
                                       tab, tbb, oww, obb, hx, w1, w2, bbw,
                                       f1w, f2w, taw, tbw,
                                       consts, w1p, w2c, bbT, HT, xb, flag);
  k_conv1<<<8192, 256, 0, stream>>>(flag, x, w1p, consts, a1s);
  k_conv2<<<2048, 256, 0, stream>>>(a1s, w2c, consts, feats);
  k_xb<<<dim3(32, 16), 256, 0, stream>>>(feats, bbT, xb);
  k_rec<<<32, 256, 0, stream>>>(flag, xb, bbT, HT, consts, rout, d_out);
  k_logits<<<8, 256, 0, stream>>>(flag, rout, consts, d_out);
}

// Round 5
// 505.521 us; speedup vs baseline: 1.1232x; 1.0909x over previous
//
#include <hip/hip_runtime.h>
#include <stdint.h>

// DoomLiquidNet: conv(3->32,k4s2p1) -> conv(32->64,k4s2p1) -> CfC core -> logits
// Inputs f32 (detected on device; bf16 fallback kept). Compute in bf16 MFMA.
//
// R5: conv2 uses global_load_lds async DMA double-buffer (no data VGPRs -> no
// scratch spill, unlike R4's register prefetch). k_xb atomics replaced by
// split-K partials + reduce. k_rec preloads xb[b] into LDS.
//
// ws layout:
//   a1s   : u32  [2048][32][32][18]  @ 0          150994944 B (dead after conv2)
//   xbp   : f32  [16][2048][128]     @ 0           16777216 B (aliases a1s)
//   feats : bf16 [2048][16384]       @ 150994944   67108864 B
//   bbT   : bf16 [128][16448]        @ 218103808    4210688 B
//   HT    : bf16 [256][128]          @ 222314496      65536 B
//   w1p   : bf16 [32][64]            @ 222380032       4096 B
//   w2c   : bf16 [64][512]           @ 222384128      65536 B
//   xb    : f32  [2048][128]         @ 222449664    1048576 B
//   rout  : f32  [2048][64]          @ 223498240     524288 B
//   consts: f32  [3048]              @ 224022528      12288 B
//   flag  : int                      @ 224034816          4 B

typedef unsigned short u16;
typedef unsigned int u32;

typedef float f32x4 __attribute__((ext_vector_type(4)));
typedef short s16x8 __attribute__((ext_vector_type(8)));
typedef __bf16 b16x8 __attribute__((ext_vector_type(8)));

template <typename V>
__device__ inline auto mfma_sel(V a, V b, f32x4 c, int)
    -> decltype(__builtin_amdgcn_mfma_f32_16x16x32_bf16(a, b, c, 0, 0, 0)) {
  return __builtin_amdgcn_mfma_f32_16x16x32_bf16(a, b, c, 0, 0, 0);
}
template <typename V>
__device__ inline f32x4 mfma_sel(V a, V b, f32x4 c, long) {
  union UU { V s; b16x8 b; };
  UU ua; ua.s = a;
  UU ub; ub.s = b;
  return __builtin_amdgcn_mfma_f32_16x16x32_bf16(ua.b, ub.b, c, 0, 0, 0);
}
__device__ inline f32x4 mfma16x16x32(s16x8 a, s16x8 b, f32x4 c) {
  return mfma_sel(a, b, c, 0);
}

__device__ inline float bf2f(u16 v) {
  union { u32 i; float f; } x; x.i = ((u32)v) << 16; return x.f;
}
__device__ inline u16 f2bf(float f) {  // round-to-nearest-even
  union { float f; u32 i; } x; x.f = f;
  u32 i = x.i;
  i += 0x7fffu + ((i >> 16) & 1u);
  return (u16)(i >> 16);
}
__device__ inline void bf2x2(u32 u, float& lo, float& hi) {
  union { u32 i; float f; } a, b;
  a.i = u << 16; b.i = u & 0xffff0000u;
  lo = a.f; hi = b.f;
}
__device__ inline float ldf(int isbf, const void* p, size_t i) {
  return isbf ? bf2f(((const u16*)p)[i]) : ((const float*)p)[i];
}
__device__ inline u16 ldb(int isbf, const void* p, size_t i) {
  return isbf ? ((const u16*)p)[i] : f2bf(((const float*)p)[i]);
}
__device__ inline float fast_tanh(float x) {
  float ax = fabsf(x);
  float e = __expf(2.0f * ax);
  float t = 1.0f - 2.0f / (e + 1.0f);
  return copysignf(t, x);
}

// ---- async global->LDS DMA, 16 B per lane. l = WAVE-UNIFORM base; HW adds
// lane*16. g = per-lane global address. ----
#if defined(__has_builtin)
#if __has_builtin(__builtin_amdgcn_global_load_lds)
#define HAVE_DMA_LDS 1
#endif
#endif
__device__ inline void dma16(const u32* g, u32* l) {
#ifdef HAVE_DMA_LDS
  __builtin_amdgcn_global_load_lds(
      (const __attribute__((address_space(1))) u32*)g,
      (__attribute__((address_space(3))) u32*)l, 16, 0, 0);
#else
  *(uint4*)((char*)l + (threadIdx.x & 63) * 16) = *(const uint4*)g;
#endif
}

// ---------- fused prep: detect + consts + w1p + w2c + bbT + HT ----------
// grid 670 blocks x 256:
//  [0,12) consts | [12,20) w1p | [20,148) w2c | [148,662) bbT | [662,670) HT
__global__ __launch_bounds__(256)
void k_prep_all(const u32* __restrict__ bwords,
                const void* b1, const void* b2, const void* bbb,
                const void* f1b, const void* f2b, const void* tab,
                const void* tbb, const void* oww, const void* obb,
                const void* hx, const void* w1, const void* w2,
                const void* bw, const void* f1w, const void* f2w,
                const void* taw, const void* tbw,
                float* __restrict__ consts, u16* __restrict__ w1p,
                u16* __restrict__ w2c, u16* __restrict__ bbT,
                u16* __restrict__ HT, int* __restrict__ flag) {
  __shared__ u16 t[64][65];
  const int tid = threadIdx.x;
  const int b = blockIdx.x;
  const u32 wd = bwords[tid & 63];
  const u32 ex = (wd >> 7) & 0xFFu;
  unsigned long long m = __ballot(ex >= 100u && ex <= 126u);
  const int isbf = (__popcll(m) >= 32) ? 1 : 0;
  if (b == 0 && tid == 0) *flag = isbf;

  if (b < 12) {
    const int e = b * 256 + tid;
    if (e >= 3048) return;
    float v;
    if (e < 32)        v = ldf(isbf, b1, e);
    else if (e < 96)   v = ldf(isbf, b2, e - 32);
    else if (e < 224)  v = ldf(isbf, bbb, e - 96);
    else if (e < 288)  v = ldf(isbf, f1b, e - 224);
    else if (e < 352)  v = ldf(isbf, f2b, e - 288);
    else if (e < 416)  v = ldf(isbf, tab, e - 352);
    else if (e < 480)  v = ldf(isbf, tbb, e - 416);
    else if (e < 992)  v = ldf(isbf, oww, e - 480);
    else if (e < 1000) v = ldf(isbf, obb, e - 992);
    else               v = ldf(isbf, hx, e - 1000);
    consts[e] = v;
  } else if (b < 20) {
    const int e = (b - 12) * 256 + tid;
    const int k = e & 63, co = e >> 6;
    w1p[e] = (k < 48) ? ldb(isbf, w1, co * 48 + k) : (u16)0;
  } else if (b < 148) {
    const int e = (b - 20) * 256 + tid;
    w2c[e] = ldb(isbf, w2, e);
  } else if (b < 662) {
    const int idx = b - 148;
    const int k0 = (idx >> 1) * 64, j0 = (idx & 1) * 64;
    #pragma unroll
    for (int i = 0; i < 16; ++i) {
      int e = tid + 256 * i;
      int kl = e >> 6, jl = e & 63;
      t[kl][jl] = ldb(isbf, bw, (size_t)(k0 + kl) * 128 + j0 + jl);
    }
    __syncthreads();
    #pragma unroll
    for (int i = 0; i < 16; ++i) {
      int e = tid + 256 * i;
      int jl = e >> 6, kl = e & 63;
      bbT[(size_t)(j0 + jl) * 16448 + k0 + kl] = t[kl][jl];
    }
  } else {
    const int idx = b - 662;
    const int h = idx >> 1, i0 = (idx & 1) * 64;
    const void* W = (h == 0) ? f1w : (h == 1) ? f2w : (h == 2) ? taw : tbw;
    #pragma unroll
    for (int i = 0; i < 16; ++i) {
      int e = tid + 256 * i;
      int il = e >> 6, cl = e & 63;
      t[il][cl] = ldb(isbf, W, (i0 + il) * 64 + cl);
    }
    __syncthreads();
    #pragma unroll
    for (int i = 0; i < 16; ++i) {
      int e = tid + 256 * i;
      int cl = e >> 6, il = e & 63;
      HT[(h * 64 + cl) * 128 + i0 + il] = t[il][cl];
    }
  }
}

// ---------- conv1: implicit GEMM; writes a1s in shifted-pair layout ----------
__global__ __launch_bounds__(256)
void k_conv1(const int* __restrict__ flagp, const void* __restrict__ x,
             const u16* __restrict__ w1p, const float* __restrict__ consts,
             u32* __restrict__ a1s) {
  __shared__ u32 lx[4 * 18 * 34];      // 9792 B
  __shared__ u32 bounce[256 * 17];     // 17408 B
  const int isbf = *flagp;
  const int n = blockIdx.x >> 2;
  const int oh0 = (blockIdx.x & 3) * 8;
  const int tid = threadIdx.x;
  for (int task = tid; task < 1152; task += 256) {
    const int row = task >> 4, tt = task & 15;
    const int ci = row / 18, ihp = row - ci * 18;
    const int ih = 2 * oh0 - 1 + ihp;
    u32* dst = &lx[row * 34];
    if (ci == 3 || ih < 0 || ih > 63) {
      dst[2 * tt] = 0u; dst[2 * tt + 1] = 0u;
      if (tt == 15) { dst[32] = 0u; dst[33] = 0u; }
    } else if (!isbf) {
      const float* src = (const float*)x + (((size_t)n * 3 + ci) * 64 + ih) * 64;
      const f32x4 v = *(const f32x4*)(src + 4 * tt);
      const float pv = tt ? src[4 * tt - 1] : 0.f;
      dst[2 * tt]     = (u32)f2bf(pv)   | (((u32)f2bf(v[0])) << 16);
      dst[2 * tt + 1] = (u32)f2bf(v[1]) | (((u32)f2bf(v[2])) << 16);
      if (tt == 15) { dst[32] = (u32)f2bf(v[3]); dst[33] = 0u; }
    } else {
      const u16* src = (const u16*)x + (((size_t)n * 3 + ci) * 64 + ih) * 64;
      const u16 v0 = src[4 * tt], v1 = src[4 * tt + 1];
      const u16 v2 = src[4 * tt + 2], v3 = src[4 * tt + 3];
      const u16 pv = tt ? src[4 * tt - 1] : (u16)0;
      dst[2 * tt]     = (u32)pv | (((u32)v0) << 16);
      dst[2 * tt + 1] = (u32)v1 | (((u32)v2) << 16);
      if (tt == 15) { dst[32] = (u32)v3; dst[33] = 0u; }
    }
  }
  __syncthreads();
  const int w = tid >> 6, lane = tid & 63, quad = lane >> 4, l15 = lane & 15;
  f32x4 acc[2][4];
  #pragma unroll
  for (int mt = 0; mt < 2; ++mt)
    #pragma unroll
    for (int i = 0; i < 4; ++i) acc[mt][i] = f32x4{0.f, 0.f, 0.f, 0.f};
  #pragma unroll
  for (int kst = 0; kst < 2; ++kst) {
    const int kbase = kst * 32 + quad * 8;
    s16x8 afrag[2];
    #pragma unroll
    for (int mt = 0; mt < 2; ++mt)
      afrag[mt] = *(const s16x8*)(w1p + (mt * 16 + l15) * 64 + kbase);
    const int ci = kbase >> 4;
    const int khb = (quad & 1) * 2;
    #pragma unroll
    for (int i = 0; i < 4; ++i) {
      const int nt = w * 4 + i;
      const int r1 = 2 * (nt >> 1) + khb;
      const int base = (ci * 18 + r1) * 34 + (nt & 1) * 16 + l15;
      union { u32 u[4]; s16x8 v; } bf;
      bf.u[0] = lx[base];
      bf.u[1] = lx[base + 1];
      bf.u[2] = lx[base + 34];
      bf.u[3] = lx[base + 35];
      #pragma unroll
      for (int mt = 0; mt < 2; ++mt)
        acc[mt][i] = mfma16x16x32(afrag[mt], bf.v, acc[mt][i]);
    }
  }
  u16* bb = (u16*)bounce;
  #pragma unroll
  for (int mt = 0; mt < 2; ++mt)
    #pragma unroll
    for (int r = 0; r < 4; ++r) {
      const int co = mt * 16 + quad * 4 + r;
      const float bias = consts[co];
      #pragma unroll
      for (int i = 0; i < 4; ++i) {
        const int nt = w * 4 + i;
        const int row = co * 8 + (nt >> 1);
        const int ow = (nt & 1) * 16 + l15;
        float v = acc[mt][i][r] + bias;
        v = v > 0.f ? v : 0.f;
        bb[row * 34 + ow] = f2bf(v);
      }
    }
  __syncthreads();
  {
    const int r = tid;
    const int co = r >> 3, oh = oh0 + (r & 7);
    const u32* wrow = &bounce[r * 17];
    u32 s[18];
    s[0] = wrow[0] << 16;
    #pragma unroll
    for (int q = 1; q < 16; ++q) s[q] = (wrow[q - 1] >> 16) | (wrow[q] << 16);
    s[16] = wrow[15] >> 16;
    s[17] = 0u;
    u32* g = a1s + (((size_t)n * 32 + co) * 32 + oh) * 18;
    #pragma unroll
    for (int q = 0; q < 9; ++q)
      *(uint2*)(g + 2 * q) = make_uint2(s[2 * q], s[2 * q + 1]);
  }
}

// ---------- conv2: async-DMA double-buffered, full image per block ----------
// LDS: [0,32) zero region | buf0 [32, 32+9216) | buf1 [+9216)  (73856 B)
// buffer layout: contiguous [ci 0..15][row 0..31][18 u32] (exact a1s slab)
__global__ __launch_bounds__(256, 2)
void k_conv2(const u32* __restrict__ a1s, const u16* __restrict__ w2c,
             const float* __restrict__ consts, u16* __restrict__ feats) {
  __shared__ u32 lx[32 + 2 * 9216];
  const int n = blockIdx.x;
  const int tid = threadIdx.x;
  const int wv = tid >> 6, lane = tid & 63, quad = lane >> 4, l15 = lane & 15;
  if (tid < 32) lx[tid] = 0u;  // zero region for border rows
  const u32* slab = a1s + (size_t)n * 32 * 576;
  // DMA half 0 -> buf0 (36 chunks of 1024 B; wave wv takes chunks wv+4i)
  #pragma unroll
  for (int i = 0; i < 9; ++i) {
    const int c = wv + 4 * i;
    dma16(slab + c * 256 + lane * 4, &lx[32 + c * 256]);
  }
  f32x4 acc[4][4];
  #pragma unroll
  for (int mt = 0; mt < 4; ++mt)
    #pragma unroll
    for (int oi = 0; oi < 4; ++oi) acc[mt][oi] = f32x4{0.f, 0.f, 0.f, 0.f};
  __syncthreads();  // buf0 ready (vmcnt drained at barrier)
  // DMA half 1 -> buf1; flies while we run half-0 MFMAs
  #pragma unroll
  for (int i = 0; i < 9; ++i) {
    const int c = wv + 4 * i;
    dma16(slab + 9216 + c * 256 + lane * 4, &lx[32 + 9216 + c * 256]);
  }
  #pragma unroll
  for (int half = 0; half < 2; ++half) {
    const int bufofs = 32 + half * 9216;
    #pragma unroll
    for (int kst = 0; kst < 8; ++kst) {
      const int kglob = half * 8 + kst;
      s16x8 afrag[4];
      #pragma unroll
      for (int mt = 0; mt < 4; ++mt)
        afrag[mt] = *(const s16x8*)(w2c + (mt * 16 + l15) * 512 + kglob * 32 + quad * 8);
      const int ci = kst * 2 + (quad >> 1);
      const int khb = (quad & 1) * 2;
      s16x8 bfrag[4];
      #pragma unroll
      for (int oi = 0; oi < 4; ++oi) {
        const int nt = wv * 4 + oi;
        const int ra = 2 * nt + khb - 1;   // in [-1, 31]
        const int rb = ra + 1;             // in [0, 32]
        const int ia = (ra >= 0) ? (bufofs + ci * 576 + ra * 18 + l15) : 0;
        const int ib = (rb <= 31) ? (bufofs + ci * 576 + rb * 18 + l15) : 0;
        union { u32 u[4]; s16x8 v; } bf;
        bf.u[0] = lx[ia];
        bf.u[1] = lx[ia + 1];
        bf.u[2] = lx[ib];
        bf.u[3] = lx[ib + 1];
        bfrag[oi] = bf.v;
      }
      #pragma unroll
      for (int mt = 0; mt < 4; ++mt)
        #pragma unroll
        for (int oi = 0; oi < 4; ++oi)
          acc[mt][oi] = mfma16x16x32(afrag[mt], bfrag[oi], acc[mt][oi]);
    }
    if (half == 0) __syncthreads();  // buf1 ready
  }
  #pragma unroll
  for (int mt = 0; mt < 4; ++mt)
    #pragma unroll
    for (int r = 0; r < 4; ++r) {
      const int co = mt * 16 + quad * 4 + r;
      const float bias = consts[32 + co];
      #pragma unroll
      for (int oi = 0; oi < 4; ++oi) {
        const int oh = wv * 4 + oi;
        float v = acc[mt][oi][r] + bias;
        v = v > 0.f ? v : 0.f;
        feats[(size_t)n * 16384 + co * 256 + oh * 16 + l15] = f2bf(v);
      }
    }
}

// ---------- xb partials: feats @ bb_w[:16384], split-K=16, NO atomics ------
__global__ __launch_bounds__(256)
void k_xb(const u16* __restrict__ feats, const u16* __restrict__ bbT,
          float* __restrict__ xbp) {
  const int m0 = blockIdx.x * 64;
  const int kc = blockIdx.y;
  const int kc0 = kc * 1024;
  const int tid = threadIdx.x;
  const int w = tid >> 6, lane = tid & 63, quad = lane >> 4, l15 = lane & 15;
  f32x4 acc[4][2];
  #pragma unroll
  for (int mt = 0; mt < 4; ++mt)
    #pragma unroll
    for (int i = 0; i < 2; ++i) acc[mt][i] = f32x4{0.f, 0.f, 0.f, 0.f};
  #pragma unroll 4
  for (int kst = 0; kst < 32; ++kst) {
    const int k = kc0 + kst * 32 + quad * 8;
    s16x8 afrag[4], bfrag[2];
    #pragma unroll
    for (int mt = 0; mt < 4; ++mt)
      afrag[mt] = *(const s16x8*)(feats + (size_t)(m0 + mt * 16 + l15) * 16384 + k);
    #pragma unroll
    for (int i = 0; i < 2; ++i)
      bfrag[i] = *(const s16x8*)(bbT + (size_t)((w * 2 + i) * 16 + l15) * 16448 + k);
    #pragma unroll
    for (int mt = 0; mt < 4; ++mt)
      #pragma unroll
      for (int i = 0; i < 2; ++i)
        acc[mt][i] = mfma16x16x32(afrag[mt], bfrag[i], acc[mt][i]);
  }
  float* dst = xbp + (size_t)kc * 262144;
  #pragma unroll
  for (int mt = 0; mt < 4; ++mt)
    #pragma unroll
    for (int i = 0; i < 2; ++i) {
      const int j = (w * 2 + i) * 16 + l15;
      #pragma unroll
      for (int r = 0; r < 4; ++r) {
        const int m = m0 + mt * 16 + quad * 4 + r;
        dst[m * 128 + j] = acc[mt][i][r];
      }
    }
}

// ---------- reduce split-K partials -> xb ----------
__global__ __launch_bounds__(256)
void k_xbsum(const float* __restrict__ xbp, float* __restrict__ xb) {
  const int e = blockIdx.x * 256 + threadIdx.x;  // 262144 total
  float s = 0.f;
  #pragma unroll
  for (int kc = 0; kc < 16; ++kc) s += xbp[(size_t)kc * 262144 + e];
  xb[e] = s;
}

// ---------- CfC recurrence: one block per batch row, 64 sequential steps ----
__global__ __launch_bounds__(256)
void k_rec(const int* __restrict__ flagp, const float* __restrict__ xb,
           const u16* __restrict__ bbT, const u16* __restrict__ HT,
           const float* __restrict__ consts, float* __restrict__ rout,
           void* __restrict__ outv) {
  __shared__ float xbl[64 * 128];  // whole xb[b] slab: 32 KB
  __shared__ float h[64];
  __shared__ float part[128];
  __shared__ float bbv[128];
  __shared__ float heads[256];
  const int isbf = *flagp;
  const int b = blockIdx.x;
  const int tid = threadIdx.x;
  const int j = tid & 127;
  const int half = tid >> 7;
  // preload this batch's xb rows (removes per-step global load from the chain)
  {
    const float* src = xb + (size_t)b * 64 * 128;
    #pragma unroll
    for (int q = 0; q < 32; ++q) xbl[q * 256 + tid] = src[q * 256 + tid];
  }
  float w1r[32];
  {
    const u32* src = (const u32*)(bbT + (size_t)j * 16448 + 16384 + half * 32);
    #pragma unroll
    for (int q = 0; q < 16; ++q) bf2x2(src[q], w1r[2 * q], w1r[2 * q + 1]);
  }
  float w2r[128];
  {
    const u32* src = (const u32*)(HT + tid * 128);
    #pragma unroll
    for (int q = 0; q < 64; ++q) bf2x2(src[q], w2r[2 * q], w2r[2 * q + 1]);
  }
  const float hbias = consts[224 + tid];
  const float bbias = consts[96 + j];
  if (tid < 64) h[tid] = consts[1000 + b * 64 + tid];
  __syncthreads();
  for (int t = 0; t < 64; ++t) {
    float p0 = 0.f, p1 = 0.f, p2 = 0.f, p3 = 0.f;
    const int hb0 = half * 32;
    #pragma unroll
    for (int q = 0; q < 8; ++q) {
      p0 += h[hb0 + 4 * q + 0] * w1r[4 * q + 0];
      p1 += h[hb0 + 4 * q + 1] * w1r[4 * q + 1];
      p2 += h[hb0 + 4 * q + 2] * w1r[4 * q + 2];
      p3 += h[hb0 + 4 * q + 3] * w1r[4 * q + 3];
    }
    const float psum = (p0 + p1) + (p2 + p3);
    if (half == 0) part[j] = psum;
    __syncthreads();
    if (half == 1) {
      const float s = psum + part[j] + xbl[t * 128 + j] + bbias;
      bbv[j] = 1.7159f * fast_tanh(0.666f * s);
    }
    __syncthreads();
    float c0 = 0.f, c1 = 0.f, c2 = 0.f, c3 = 0.f;
    #pragma unroll
    for (int q = 0; q < 32; ++q) {
      c0 += bbv[4 * q + 0] * w2r[4 * q + 0];
      c1 += bbv[4 * q + 1] * w2r[4 * q + 1];
      c2 += bbv[4 * q + 2] * w2r[4 * q + 2];
      c3 += bbv[4 * q + 3] * w2r[4 * q + 3];
    }
    heads[tid] = (c0 + c1) + (c2 + c3) + hbias;
    __syncthreads();
    if (tid < 64) {
      const float ff1 = fast_tanh(heads[tid]);
      const float ff2 = fast_tanh(heads[64 + tid]);
      const float ti = 1.f / (1.f + __expf(-(heads[128 + tid] + heads[192 + tid])));
      const float hn = ff1 * (1.f - ti) + ti * ff2;
      h[tid] = hn;
      rout[((size_t)b * 64 + t) * 64 + tid] = hn;
    }
    __syncthreads();
  }
  if (tid < 64) {
    if (isbf) ((u16*)outv)[16384 + b * 64 + tid] = f2bf(h[tid]);
    else      ((float*)outv)[16384 + b * 64 + tid] = h[tid];
  }
}

// ---------- logits = rout @ out_w + out_b ----------
__global__ __launch_bounds__(256)
void k_logits(const int* __restrict__ flagp, const float* __restrict__ rout,
              const float* __restrict__ consts, void* __restrict__ outv) {
  __shared__ float W[512];
  __shared__ float Bv[8];
  const int isbf = *flagp;
  const int tid = threadIdx.x;
  for (int e = tid; e < 512; e += 256) W[e] = consts[480 + e];
  if (tid < 8) Bv[tid] = consts[992 + tid];
  __syncthreads();
  const int bt = blockIdx.x * 256 + tid;
  float acc[8];
  #pragma unroll
  for (int c = 0; c < 8; ++c) acc[c] = Bv[c];
  const f32x4* r = (const f32x4*)(rout + (size_t)bt * 64);
  #pragma unroll
  for (int q = 0; q < 16; ++q) {
    f32x4 v = r[q];
    #pragma unroll
    for (int u = 0; u < 4; ++u) {
      const float rv = v[u];
      const int i = 4 * q + u;
      #pragma unroll
      for (int c = 0; c < 8; ++c) acc[c] += rv * W[i * 8 + c];
    }
  }
  if (isbf) {
    u32 pk[4];
    #pragma unroll
    for (int c = 0; c < 4; ++c)
      pk[c] = (u32)f2bf(acc[2 * c]) | ((u32)f2bf(acc[2 * c + 1]) << 16);
    *(uint4*)((u16*)outv + (size_t)bt * 8) = *(const uint4*)pk;
  } else {
    float* o = (float*)outv + (size_t)bt * 8;
    *(f32x4*)o = f32x4{acc[0], acc[1], acc[2], acc[3]};
    *(f32x4*)(o + 4) = f32x4{acc[4], acc[5], acc[6], acc[7]};
  }
}

extern "C" void kernel_launch(void* const* d_in, const int* in_sizes, int n_in,
                              void* d_out, int out_size, void* d_ws, size_t ws_size,
                              hipStream_t stream) {
  const void* x   = d_in[0];
  const void* hx  = d_in[1];
  const void* w1  = d_in[2];
  const void* b1  = d_in[3];
  const void* w2  = d_in[4];
  const void* b2  = d_in[5];
  const void* bbw = d_in[6];
  const void* bbb = d_in[7];
  const void* f1w = d_in[8];
  const void* f1b = d_in[9];
  const void* f2w = d_in[10];
  const void* f2b = d_in[11];
  const void* taw = d_in[12];
  const void* tab = d_in[13];
  const void* tbw = d_in[14];
  const void* tbb = d_in[15];
  const void* oww = d_in[16];
  const void* obb = d_in[17];

  char* ws = (char*)d_ws;
  u32*   a1s   = (u32*)(ws);
  float* xbp   = (float*)(ws);            // aliases a1s (dead after conv2)
  u16*   feats = (u16*)(ws + 150994944);
  u16*   bbT   = (u16*)(ws + 218103808);
  u16*   HT    = (u16*)(ws + 222314496);
  u16*   w1p   = (u16*)(ws + 222380032);
  u16*   w2c   = (u16*)(ws + 222384128);
  float* xb    = (float*)(ws + 222449664);
  float* rout  = (float*)(ws + 223498240);
  float* consts= (float*)(ws + 224022528);
  int*   flag  = (int*)(ws + 224034816);

  k_prep_all<<<670, 256, 0, stream>>>((const u32*)bbw, b1, b2, bbb, f1b, f2b,
                                      tab, tbb, oww, obb, hx, w1, w2, bbw,
                                      f1w, f2w, taw, tbw,
                                      consts, w1p, w2c, bbT, HT, flag);
  k_conv1<<<8192, 256, 0, stream>>>(flag, x, w1p, consts, a1s);
  k_conv2<<<2048, 256, 0, stream>>>(a1s, w2c, consts, feats);
  k_xb<<<dim3(32, 16), 256, 0, stream>>>(feats, bbT, xbp);
  k_xbsum<<<1024, 256, 0, stream>>>(xbp, xb);
  k_rec<<<32, 256, 0, stream>>>(flag, xb, bbT, HT, consts, rout, d_out);
  k_logits<<<8, 256, 0, stream>>>(flag, rout, consts, d_out);
}

// Round 6
// 490.201 us; speedup vs baseline: 1.1584x; 1.0313x over previous
//
#include <hip/hip_runtime.h>
#include <stdint.h>

// DoomLiquidNet: conv(3->32,k4s2p1) -> conv(32->64,k4s2p1) -> CfC core -> logits
// Inputs f32 (detected on device; bf16 fallback kept). Compute in bf16 MFMA.
//
// R6: conv1+conv2 FUSED into k_convs (one block per image, 512 thr):
//   x staged in LDS (shifted-pair bf16), conv1 writes a1-half into LDS,
//   conv2 consumes it in K-halves -> a1 never hits HBM (saves ~300 MB RT).
//   conv1 uses one f32x4 acc per n-tile to stay under 128 VGPR (R4 lesson:
//   register prefetch blobs -> scratch spill). k_rec: 3 barriers/step.
//
// ws layout:
//   xbp   : f32  [16][2048][128]     @ 0           16777216 B
//   feats : bf16 [2048][16384]       @ 150994944   67108864 B
//   bbT   : bf16 [128][16448]        @ 218103808    4210688 B
//   HT    : bf16 [256][128]          @ 222314496      65536 B
//   w1p   : bf16 [32][64]            @ 222380032       4096 B
//   w2c   : bf16 [64][512]           @ 222384128      65536 B
//   xb    : f32  [2048][128]         @ 222449664    1048576 B
//   rout  : f32  [2048][64]          @ 223498240     524288 B
//   consts: f32  [3048]              @ 224022528      12288 B
//   flag  : int                      @ 224034816          4 B

typedef unsigned short u16;
typedef unsigned int u32;

typedef float f32x4 __attribute__((ext_vector_type(4)));
typedef short s16x8 __attribute__((ext_vector_type(8)));
typedef __bf16 b16x8 __attribute__((ext_vector_type(8)));

template <typename V>
__device__ inline auto mfma_sel(V a, V b, f32x4 c, int)
    -> decltype(__builtin_amdgcn_mfma_f32_16x16x32_bf16(a, b, c, 0, 0, 0)) {
  return __builtin_amdgcn_mfma_f32_16x16x32_bf16(a, b, c, 0, 0, 0);
}
template <typename V>
__device__ inline f32x4 mfma_sel(V a, V b, f32x4 c, long) {
  union UU { V s; b16x8 b; };
  UU ua; ua.s = a;
  UU ub; ub.s = b;
  return __builtin_amdgcn_mfma_f32_16x16x32_bf16(ua.b, ub.b, c, 0, 0, 0);
}
__device__ inline f32x4 mfma16x16x32(s16x8 a, s16x8 b, f32x4 c) {
  return mfma_sel(a, b, c, 0);
}

__device__ inline float bf2f(u16 v) {
  union { u32 i; float f; } x; x.i = ((u32)v) << 16; return x.f;
}
__device__ inline u16 f2bf(float f) {  // round-to-nearest-even
  union { float f; u32 i; } x; x.f = f;
  u32 i = x.i;
  i += 0x7fffu + ((i >> 16) & 1u);
  return (u16)(i >> 16);
}
__device__ inline void bf2x2(u32 u, float& lo, float& hi) {
  union { u32 i; float f; } a, b;
  a.i = u << 16; b.i = u & 0xffff0000u;
  lo = a.f; hi = b.f;
}
__device__ inline float ldf(int isbf, const void* p, size_t i) {
  return isbf ? bf2f(((const u16*)p)[i]) : ((const float*)p)[i];
}
__device__ inline u16 ldb(int isbf, const void* p, size_t i) {
  return isbf ? ((const u16*)p)[i] : f2bf(((const float*)p)[i]);
}
__device__ inline float fast_tanh(float x) {
  float ax = fabsf(x);
  float e = __expf(2.0f * ax);
  float t = 1.0f - 2.0f / (e + 1.0f);
  return copysignf(t, x);
}

// ---------- fused prep: detect + consts + w1p + w2c + bbT + HT ----------
__global__ __launch_bounds__(256)
void k_prep_all(const u32* __restrict__ bwords,
                const void* b1, const void* b2, const void* bbb,
                const void* f1b, const void* f2b, const void* tab,
                const void* tbb, const void* oww, const void* obb,
                const void* hx, const void* w1, const void* w2,
                const void* bw, const void* f1w, const void* f2w,
                const void* taw, const void* tbw,
                float* __restrict__ consts, u16* __restrict__ w1p,
                u16* __restrict__ w2c, u16* __restrict__ bbT,
                u16* __restrict__ HT, int* __restrict__ flag) {
  __shared__ u16 t[64][65];
  const int tid = threadIdx.x;
  const int b = blockIdx.x;
  const u32 wd = bwords[tid & 63];
  const u32 ex = (wd >> 7) & 0xFFu;
  unsigned long long m = __ballot(ex >= 100u && ex <= 126u);
  const int isbf = (__popcll(m) >= 32) ? 1 : 0;
  if (b == 0 && tid == 0) *flag = isbf;

  if (b < 12) {
    const int e = b * 256 + tid;
    if (e >= 3048) return;
    float v;
    if (e < 32)        v = ldf(isbf, b1, e);
    else if (e < 96)   v = ldf(isbf, b2, e - 32);
    else if (e < 224)  v = ldf(isbf, bbb, e - 96);
    else if (e < 288)  v = ldf(isbf, f1b, e - 224);
    else if (e < 352)  v = ldf(isbf, f2b, e - 288);
    else if (e < 416)  v = ldf(isbf, tab, e - 352);
    else if (e < 480)  v = ldf(isbf, tbb, e - 416);
    else if (e < 992)  v = ldf(isbf, oww, e - 480);
    else if (e < 1000) v = ldf(isbf, obb, e - 992);
    else               v = ldf(isbf, hx, e - 1000);
    consts[e] = v;
  } else if (b < 20) {
    const int e = (b - 12) * 256 + tid;
    const int k = e & 63, co = e >> 6;
    w1p[e] = (k < 48) ? ldb(isbf, w1, co * 48 + k) : (u16)0;
  } else if (b < 148) {
    const int e = (b - 20) * 256 + tid;
    w2c[e] = ldb(isbf, w2, e);
  } else if (b < 662) {
    const int idx = b - 148;
    const int k0 = (idx >> 1) * 64, j0 = (idx & 1) * 64;
    #pragma unroll
    for (int i = 0; i < 16; ++i) {
      int e = tid + 256 * i;
      int kl = e >> 6, jl = e & 63;
      t[kl][jl] = ldb(isbf, bw, (size_t)(k0 + kl) * 128 + j0 + jl);
    }
    __syncthreads();
    #pragma unroll
    for (int i = 0; i < 16; ++i) {
      int e = tid + 256 * i;
      int jl = e >> 6, kl = e & 63;
      bbT[(size_t)(j0 + jl) * 16448 + k0 + kl] = t[kl][jl];
    }
  } else {
    const int idx = b - 662;
    const int h = idx >> 1, i0 = (idx & 1) * 64;
    const void* W = (h == 0) ? f1w : (h == 1) ? f2w : (h == 2) ? taw : tbw;
    #pragma unroll
    for (int i = 0; i < 16; ++i) {
      int e = tid + 256 * i;
      int il = e >> 6, cl = e & 63;
      t[il][cl] = ldb(isbf, W, (i0 + il) * 64 + cl);
    }
    __syncthreads();
    #pragma unroll
    for (int i = 0; i < 16; ++i) {
      int e = tid + 256 * i;
      int cl = e >> 6, il = e & 63;
      HT[(h * 64 + cl) * 128 + i0 + il] = t[il][cl];
    }
  }
}

// ---------- fused conv1+conv2: one image per block, a1 stays in LDS ----------
// LDS u32 map:
//   XS   @ 0     : 3 planes x 66 rows x 34 u32 (shifted-pair, rows 0/65 = 0)
//   ZS   @ 6732  : 68 u32 zeros (conv1 K-pad plane reads)
//   A1H  @ 6800  : 16 planes x 34 rows x 18 u32 (shifted-pair, rows 0/33 = 0)
//   total 16592 u32 = 66368 B  -> 2 blocks/CU
__global__ __launch_bounds__(512, 4)
void k_convs(const int* __restrict__ flagp, const void* __restrict__ x,
             const u16* __restrict__ w1p, const u16* __restrict__ w2c,
             const float* __restrict__ consts, u16* __restrict__ feats) {
  __shared__ u32 lx[16592];
  const int isbf = *flagp;
  const int n = blockIdx.x;
  const int tid = threadIdx.x;
  const int wv = tid >> 6, lane = tid & 63, quad = lane >> 4, l15 = lane & 15;

  // zero: xs border rows + zero strip + whole a1h (disjoint from staging)
  for (int e = tid; e < 10064; e += 512) {
    int idx;
    if (e < 204) {
      const int pl = e / 68;
      const int rem = e - pl * 68;
      const int r = rem / 34;
      idx = pl * 2244 + r * (65 * 34) + (rem - r * 34);
    } else if (e < 272) {
      idx = 6732 + (e - 204);
    } else {
      idx = 6800 + (e - 272);
    }
    lx[idx] = 0u;
  }
  // stage x -> XS (interior rows 1..64), shifted-pair bf16
  for (int e = tid; e < 3072; e += 512) {
    const int ci = e >> 10;
    const int rr = (e >> 4) & 63;
    const int tt = e & 15;
    u32* dst = &lx[(ci * 66 + rr + 1) * 34];
    if (!isbf) {
      const float* src = (const float*)x + (((size_t)n * 3 + ci) * 64 + rr) * 64 + 4 * tt;
      const f32x4 v = *(const f32x4*)src;
      const float pv = tt ? src[-1] : 0.f;
      dst[2 * tt]     = (u32)f2bf(pv)   | (((u32)f2bf(v[0])) << 16);
      dst[2 * tt + 1] = (u32)f2bf(v[1]) | (((u32)f2bf(v[2])) << 16);
      if (tt == 15) { dst[32] = (u32)f2bf(v[3]); dst[33] = 0u; }
    } else {
      const u16* src = (const u16*)x + (((size_t)n * 3 + ci) * 64 + rr) * 64 + 4 * tt;
      const u16 pv = tt ? src[-1] : (u16)0;
      dst[2 * tt]     = (u32)pv | (((u32)src[0]) << 16);
      dst[2 * tt + 1] = (u32)src[1] | (((u32)src[2]) << 16);
      if (tt == 15) { dst[32] = (u32)src[3]; dst[33] = 0u; }
    }
  }
  __syncthreads();

  f32x4 acc2[4][2];
  #pragma unroll
  for (int mt = 0; mt < 4; ++mt)
    #pragma unroll
    for (int oi = 0; oi < 2; ++oi) acc2[mt][oi] = f32x4{0.f, 0.f, 0.f, 0.f};

  const int khb = (quad & 1) * 2;
  const int cih = quad >> 1;
  u16* lp = (u16*)lx;

  #pragma unroll
  for (int h = 0; h < 2; ++h) {
    // ---- conv1 half: co = h*16 .. h*16+15 -> A1H ----
    const s16x8 af0 = *(const s16x8*)(w1p + (h * 16 + l15) * 64 + quad * 8);
    const s16x8 af1 = *(const s16x8*)(w1p + (h * 16 + l15) * 64 + 32 + quad * 8);
    #pragma unroll
    for (int i = 0; i < 8; ++i) {
      const int nt = wv * 8 + i;
      const int oh = nt >> 1;
      const int ob = (nt & 1) * 16;
      f32x4 a1acc = f32x4{0.f, 0.f, 0.f, 0.f};
      {
        const int base = (cih * 66 + 2 * oh + khb) * 34 + ob + l15;
        union { u32 u[4]; s16x8 v; } bf;
        bf.u[0] = lx[base];
        bf.u[1] = lx[base + 1];
        bf.u[2] = lx[base + 34];
        bf.u[3] = lx[base + 35];
        a1acc = mfma16x16x32(af0, bf.v, a1acc);
      }
      {
        const int ci1 = 2 + cih;  // 2 or 3 (3 = K-pad -> zero strip)
        const int base = (ci1 < 3) ? ((ci1 * 66 + 2 * oh + khb) * 34 + ob + l15)
                                   : (6732 + ob + l15);
        union { u32 u[4]; s16x8 v; } bf;
        bf.u[0] = lx[base];
        bf.u[1] = lx[base + 1];
        bf.u[2] = lx[base + 34];
        bf.u[3] = lx[base + 35];
        a1acc = mfma16x16x32(af1, bf.v, a1acc);
      }
      #pragma unroll
      for (int r = 0; r < 4; ++r) {
        const int co = quad * 4 + r;
        float v = a1acc[r] + consts[h * 16 + co];
        v = v > 0.f ? v : 0.f;
        lp[(6800 + (co * 34 + oh + 1) * 18) * 2 + ob + l15 + 1] = f2bf(v);
      }
    }
    __syncthreads();  // a1 half ready
    // ---- conv2 K-half: planes 16h..16h+15 ----
    #pragma unroll
    for (int kst = 0; kst < 8; ++kst) {
      const int kglob = h * 8 + kst;
      s16x8 afr[4];
      #pragma unroll
      for (int mt = 0; mt < 4; ++mt)
        afr[mt] = *(const s16x8*)(w2c + (mt * 16 + l15) * 512 + kglob * 32 + quad * 8);
      const int ci = kst * 2 + cih;
      s16x8 bfr[2];
      #pragma unroll
      for (int oi = 0; oi < 2; ++oi) {
        const int row1 = 2 * (wv * 2 + oi) + khb;
        const int base = 6800 + (ci * 34 + row1) * 18 + l15;
        union { u32 u[4]; s16x8 v; } bf;
        bf.u[0] = lx[base];
        bf.u[1] = lx[base + 1];
        bf.u[2] = lx[base + 18];
        bf.u[3] = lx[base + 19];
        bfr[oi] = bf.v;
      }
      #pragma unroll
      for (int mt = 0; mt < 4; ++mt)
        #pragma unroll
        for (int oi = 0; oi < 2; ++oi)
          acc2[mt][oi] = mfma16x16x32(afr[mt], bfr[oi], acc2[mt][oi]);
    }
    if (h == 0) __syncthreads();  // conv2 h0 done reading before conv1 h1 writes
  }
  // ---- epilogue: feats ----
  #pragma unroll
  for (int mt = 0; mt < 4; ++mt)
    #pragma unroll
    for (int r = 0; r < 4; ++r) {
      const int co = mt * 16 + quad * 4 + r;
      const float bias = consts[32 + co];
      #pragma unroll
      for (int oi = 0; oi < 2; ++oi) {
        const int oh = wv * 2 + oi;
        float v = acc2[mt][oi][r] + bias;
        v = v > 0.f ? v : 0.f;
        feats[(size_t)n * 16384 + co * 256 + oh * 16 + l15] = f2bf(v);
      }
    }
}

// ---------- xb partials: feats @ bb_w[:16384], split-K=16, NO atomics ------
__global__ __launch_bounds__(256)
void k_xb(const u16* __restrict__ feats, const u16* __restrict__ bbT,
          float* __restrict__ xbp) {
  const int m0 = blockIdx.x * 64;
  const int kc = blockIdx.y;
  const int kc0 = kc * 1024;
  const int tid = threadIdx.x;
  const int w = tid >> 6, lane = tid & 63, quad = lane >> 4, l15 = lane & 15;
  f32x4 acc[4][2];
  #pragma unroll
  for (int mt = 0; mt < 4; ++mt)
    #pragma unroll
    for (int i = 0; i < 2; ++i) acc[mt][i] = f32x4{0.f, 0.f, 0.f, 0.f};
  #pragma unroll 4
  for (int kst = 0; kst < 32; ++kst) {
    const int k = kc0 + kst * 32 + quad * 8;
    s16x8 afrag[4], bfrag[2];
    #pragma unroll
    for (int mt = 0; mt < 4; ++mt)
      afrag[mt] = *(const s16x8*)(feats + (size_t)(m0 + mt * 16 + l15) * 16384 + k);
    #pragma unroll
    for (int i = 0; i < 2; ++i)
      bfrag[i] = *(const s16x8*)(bbT + (size_t)((w * 2 + i) * 16 + l15) * 16448 + k);
    #pragma unroll
    for (int mt = 0; mt < 4; ++mt)
      #pragma unroll
      for (int i = 0; i < 2; ++i)
        acc[mt][i] = mfma16x16x32(afrag[mt], bfrag[i], acc[mt][i]);
  }
  float* dst = xbp + (size_t)kc * 262144;
  #pragma unroll
  for (int mt = 0; mt < 4; ++mt)
    #pragma unroll
    for (int i = 0; i < 2; ++i) {
      const int j = (w * 2 + i) * 16 + l15;
      #pragma unroll
      for (int r = 0; r < 4; ++r) {
        const int m = m0 + mt * 16 + quad * 4 + r;
        dst[m * 128 + j] = acc[mt][i][r];
      }
    }
}

// ---------- reduce split-K partials -> xb ----------
__global__ __launch_bounds__(256)
void k_xbsum(const float* __restrict__ xbp, float* __restrict__ xb) {
  const int e = blockIdx.x * 256 + threadIdx.x;
  float s = 0.f;
  #pragma unroll
  for (int kc = 0; kc < 16; ++kc) s += xbp[(size_t)kc * 262144 + e];
  xb[e] = s;
}

// ---------- CfC recurrence: one block per batch row, 3 barriers/step ----------
__global__ __launch_bounds__(256)
void k_rec(const int* __restrict__ flagp, const float* __restrict__ xb,
           const u16* __restrict__ bbT, const u16* __restrict__ HT,
           const float* __restrict__ consts, float* __restrict__ rout,
           void* __restrict__ outv) {
  __shared__ float xbl[64 * 128];
  __shared__ float h[64];
  __shared__ float bbv[128];
  __shared__ float heads[256];
  const int isbf = *flagp;
  const int b = blockIdx.x;
  const int tid = threadIdx.x;
  {
    const float* src = xb + (size_t)b * 64 * 128;
    #pragma unroll
    for (int q = 0; q < 32; ++q) xbl[q * 256 + tid] = src[q * 256 + tid];
  }
  // phase-1 weights: full K=64 column for j = tid (threads 0..127)
  float w1r[64];
  if (tid < 128) {
    const u32* src = (const u32*)(bbT + (size_t)tid * 16448 + 16384);
    #pragma unroll
    for (int q = 0; q < 32; ++q) bf2x2(src[q], w1r[2 * q], w1r[2 * q + 1]);
  }
  float w2r[128];
  {
    const u32* src = (const u32*)(HT + tid * 128);
    #pragma unroll
    for (int q = 0; q < 64; ++q) bf2x2(src[q], w2r[2 * q], w2r[2 * q + 1]);
  }
  const float hbias = consts[224 + tid];
  const float bbias = (tid < 128) ? consts[96 + tid] : 0.f;
  if (tid < 64) h[tid] = consts[1000 + b * 64 + tid];
  __syncthreads();
  for (int t = 0; t < 64; ++t) {
    if (tid < 128) {
      float p0 = 0.f, p1 = 0.f, p2 = 0.f, p3 = 0.f;
      #pragma unroll
      for (int q = 0; q < 16; ++q) {
        p0 += h[4 * q + 0] * w1r[4 * q + 0];
        p1 += h[4 * q + 1] * w1r[4 * q + 1];
        p2 += h[4 * q + 2] * w1r[4 * q + 2];
        p3 += h[4 * q + 3] * w1r[4 * q + 3];
      }
      const float s = (p0 + p1) + (p2 + p3) + xbl[t * 128 + tid] + bbias;
      bbv[tid] = 1.7159f * fast_tanh(0.666f * s);
    }
    __syncthreads();
    float c0 = 0.f, c1 = 0.f, c2 = 0.f, c3 = 0.f;
    #pragma unroll
    for (int q = 0; q < 32; ++q) {
      c0 += bbv[4 * q + 0] * w2r[4 * q + 0];
      c1 += bbv[4 * q + 1] * w2r[4 * q + 1];
      c2 += bbv[4 * q + 2] * w2r[4 * q + 2];
      c3 += bbv[4 * q + 3] * w2r[4 * q + 3];
    }
    heads[tid] = (c0 + c1) + (c2 + c3) + hbias;
    __syncthreads();
    if (tid < 64) {
      const float ff1 = fast_tanh(heads[tid]);
      const float ff2 = fast_tanh(heads[64 + tid]);
      const float ti = 1.f / (1.f + __expf(-(heads[128 + tid] + heads[192 + tid])));
      const float hn = ff1 * (1.f - ti) + ti * ff2;
      h[tid] = hn;
      rout[((size_t)b * 64 + t) * 64 + tid] = hn;
    }
    __syncthreads();
  }
  if (tid < 64) {
    if (isbf) ((u16*)outv)[16384 + b * 64 + tid] = f2bf(h[tid]);
    else      ((float*)outv)[16384 + b * 64 + tid] = h[tid];
  }
}

// ---------- logits = rout @ out_w + out_b ----------
__global__ __launch_bounds__(256)
void k_logits(const int* __restrict__ flagp, const float* __restrict__ rout,
              const float* __restrict__ consts, void* __restrict__ outv) {
  __shared__ float W[512];
  __shared__ float Bv[8];
  const int isbf = *flagp;
  const int tid = threadIdx.x;
  for (int e = tid; e < 512; e += 256) W[e] = consts[480 + e];
  if (tid < 8) Bv[tid] = consts[992 + tid];
  __syncthreads();
  const int bt = blockIdx.x * 256 + tid;
  float acc[8];
  #pragma unroll
  for (int c = 0; c < 8; ++c) acc[c] = Bv[c];
  const f32x4* r = (const f32x4*)(rout + (size_t)bt * 64);
  #pragma unroll
  for (int q = 0; q < 16; ++q) {
    f32x4 v = r[q];
    #pragma unroll
    for (int u = 0; u < 4; ++u) {
      const float rv = v[u];
      const int i = 4 * q + u;
      #pragma unroll
      for (int c = 0; c < 8; ++c) acc[c] += rv * W[i * 8 + c];
    }
  }
  if (isbf) {
    u32 pk[4];
    #pragma unroll
    for (int c = 0; c < 4; ++c)
      pk[c] = (u32)f2bf(acc[2 * c]) | ((u32)f2bf(acc[2 * c + 1]) << 16);
    *(uint4*)((u16*)outv + (size_t)bt * 8) = *(const uint4*)pk;
  } else {
    float* o = (float*)outv + (size_t)bt * 8;
    *(f32x4*)o = f32x4{acc[0], acc[1], acc[2], acc[3]};
    *(f32x4*)(o + 4) = f32x4{acc[4], acc[5], acc[6], acc[7]};
  }
}

extern "C" void kernel_launch(void* const* d_in, const int* in_sizes, int n_in,
                              void* d_out, int out_size, void* d_ws, size_t ws_size,
                              hipStream_t stream) {
  const void* x   = d_in[0];
  const void* hx  = d_in[1];
  const void* w1  = d_in[2];
  const void* b1  = d_in[3];
  const void* w2  = d_in[4];
  const void* b2  = d_in[5];
  const void* bbw = d_in[6];
  const void* bbb = d_in[7];
  const void* f1w = d_in[8];
  const void* f1b = d_in[9];
  const void* f2w = d_in[10];
  const void* f2b = d_in[11];
  const void* taw = d_in[12];
  const void* tab = d_in[13];
  const void* tbw = d_in[14];
  const void* tbb = d_in[15];
  const void* oww = d_in[16];
  const void* obb = d_in[17];

  char* ws = (char*)d_ws;
  float* xbp   = (float*)(ws);
  u16*   feats = (u16*)(ws + 150994944);
  u16*   bbT   = (u16*)(ws + 218103808);
  u16*   HT    = (u16*)(ws + 222314496);
  u16*   w1p   = (u16*)(ws + 222380032);
  u16*   w2c   = (u16*)(ws + 222384128);
  float* xb    = (float*)(ws + 222449664);
  float* rout  = (float*)(ws + 223498240);
  float* consts= (float*)(ws + 224022528);
  int*   flag  = (int*)(ws + 224034816);

  k_prep_all<<<670, 256, 0, stream>>>((const u32*)bbw, b1, b2, bbb, f1b, f2b,
                                      tab, tbb, oww, obb, hx, w1, w2, bbw,
                                      f1w, f2w, taw, tbw,
                                      consts, w1p, w2c, bbT, HT, flag);
  k_convs<<<2048, 512, 0, stream>>>(flag, x, w1p, w2c, consts, feats);
  k_xb<<<dim3(32, 16), 256, 0, stream>>>(feats, bbT, xbp);
  k_xbsum<<<1024, 256, 0, stream>>>(xbp, xb);
  k_rec<<<32, 256, 0, stream>>>(flag, xb, bbT, HT, consts, rout, d_out);
  k_logits<<<8, 256, 0, stream>>>(flag, rout, consts, d_out);
}